// Round 7
// baseline (938.394 us; speedup 1.0000x reference)
//
#include <hip/hip_runtime.h>
#include <math.h>

#define NN 50000
#define EE 800000
#define NEG 0.2f

using f32x4  = __attribute__((ext_vector_type(4))) float;
using bf16x8 = __attribute__((ext_vector_type(8))) short;

__device__ __forceinline__ float lrelu(float x){ return x > 0.f ? x : NEG*x; }

__device__ __forceinline__ unsigned short f2b(float f){
    unsigned int u = __float_as_uint(f);
    return (unsigned short)((u + 0x7FFFu + ((u >> 16) & 1u)) >> 16);  // RNE
}
__device__ __forceinline__ float b2f(unsigned short h){
    return __uint_as_float(((unsigned int)h) << 16);
}
__device__ __forceinline__ void gld_lds16(const void* g, void* l){
    __builtin_amdgcn_global_load_lds(
        (const __attribute__((address_space(1))) unsigned int*)g,
        (__attribute__((address_space(3))) unsigned int*)l, 16, 0, 0);
}

// ---------------------------------------------------------------------------
// Weight packers (fragment-order bf16).
// Fusion: chunk = ct*4 + r  (frag chunk index). k < K-1 only (ones-row via init).
// ---------------------------------------------------------------------------
__global__ void pack_w_fusion(const float* __restrict__ W, unsigned short* __restrict__ out,
                              int K, int NKC)
{
    int u = blockIdx.x * blockDim.x + threadIdx.x;
    if (u >= NKC * 16 * 64) return;
    int l = u & 63, chunk = (u >> 6) & 15, kc = u >> 10;
    int ct = chunk >> 2, r = chunk & 3;
    int c = ct * 16 + (l & 15);
    int kb = kc * 32 + (l >> 4) * 8;
    bf16x8 v;
#pragma unroll
    for (int j = 0; j < 8; ++j)
        v[j] = (short)f2b(W[((size_t)r * K + kb + j) * 64 + c]);
    *(bf16x8*)(out + (size_t)u * 8) = v;
}

// GEMM weights: chunk = ct (C/16 chunks); K multiple of 32.
__global__ void pack_w_gemm(const float* __restrict__ W, unsigned short* __restrict__ out,
                            int K, int C)
{
    int NCH = C / 16;
    int total = (K / 32) * NCH * 64;
    int u = blockIdx.x * blockDim.x + threadIdx.x;
    if (u >= total) return;
    int l = u & 63, ch = (u >> 6) % NCH, kc = u / (64 * NCH);
    int c = ch * 16 + (l & 15);
    int kb = kc * 32 + (l >> 4) * 8;
    bf16x8 v;
#pragma unroll
    for (int j = 0; j < 8; ++j)
        v[j] = (short)f2b(W[(size_t)(kb + j) * C + c]);
    *(bf16x8*)(out + (size_t)u * 8) = v;
}

// ---------------------------------------------------------------------------
// pack_a: f32 features -> bf16 A-fragment order [group][kc][lane][8]
//   element: node = g*16 + (l&15), k = kc*32 + (l>>4)*8 + j   (k < K-1 only)
// Block = one 16-node group. Reads coalesced along K, LDS transpose,
// writes perfectly coalesced (lane-linear 16B).
// ---------------------------------------------------------------------------
template<int K, int NKC>
__global__ __launch_bounds__(256) void pack_a(
    const float* __restrict__ F, unsigned short* __restrict__ out)
{
    __shared__ float sf[16][K + 3];
    const int tid = threadIdx.x;
    const int g = blockIdx.x, nb = g * 16;

    for (int idx = tid; idx < 16 * K; idx += 256) {
        int row = idx / K, k = idx - row * K;
        sf[row][k] = F[(size_t)(nb + row) * K + k];
    }
    __syncthreads();

    for (int v = tid; v < NKC * 64; v += 256) {
        int kc = v >> 6, l = v & 63;
        int row = l & 15, kb = kc * 32 + (l >> 4) * 8;
        bf16x8 o;
#pragma unroll
        for (int j = 0; j < 8; ++j) o[j] = (short)f2b(sf[row][kb + j]);
        *(bf16x8*)(out + ((size_t)(g * NKC + kc) * 64 + l) * 8) = o;
    }
}

// ---------------------------------------------------------------------------
// Fusion: barrier-free, LDS-free. One wave = 16 nodes x 64 cols, all 4 ranks.
// A-frag: 1 coalesced bf16x8 load/lane from packed ap. B-frags: 16 loads from
// packed wp (same addresses for all waves -> L1-resident).
// acc initialized from the ones-row W[r][K-1][c] (exact f32).
// ---------------------------------------------------------------------------
template<int K, int NKC>
__device__ __forceinline__ void fusion_pass_pk(
    const unsigned short* __restrict__ ap, const unsigned short* __restrict__ wp,
    const float* __restrict__ W, int G, int l, f32x4 (&acc)[4][4])
{
    const int c_lo = l & 15;
#pragma unroll
    for (int r = 0; r < 4; ++r)
#pragma unroll
        for (int ct = 0; ct < 4; ++ct) {
            float wi = W[((size_t)r * K + (K - 1)) * 64 + ct * 16 + c_lo];
            acc[r][ct] = f32x4{wi, wi, wi, wi};
        }

    const unsigned short* abase = ap + ((size_t)G * NKC * 64 + l) * 8;
#pragma unroll
    for (int kc = 0; kc < NKC; ++kc) {
        bf16x8 af = *(const bf16x8*)(abase + (size_t)kc * 64 * 8);
        const unsigned short* wk = wp + (size_t)kc * 8192 + l * 8;
#pragma unroll
        for (int ct = 0; ct < 4; ++ct)
#pragma unroll
            for (int r = 0; r < 4; ++r) {
                bf16x8 bf = *(const bf16x8*)(wk + (ct * 4 + r) * 512);
                acc[r][ct] = __builtin_amdgcn_mfma_f32_16x16x32_bf16(af, bf, acc[r][ct], 0, 0, 0);
            }
    }
}

__global__ __launch_bounds__(256) void fusion_mfma(
    const unsigned short* __restrict__ apc, const unsigned short* __restrict__ apt,
    const unsigned short* __restrict__ apr,
    const unsigned short* __restrict__ wpc, const unsigned short* __restrict__ wpt,
    const unsigned short* __restrict__ wpr,
    const float* __restrict__ Wc, const float* __restrict__ Wt, const float* __restrict__ Wr,
    const float* __restrict__ fw, const float* __restrict__ fb,
    unsigned short* __restrict__ h0b)
{
    const int G = blockIdx.x * 4 + (threadIdx.x >> 6);
    if (G >= NN / 16) return;
    const int l = threadIdx.x & 63;

    f32x4 prod[4][4], acc[4][4];
    fusion_pass_pk<129, 4>(apc, wpc, Wc, G, l, acc);
#pragma unroll
    for (int r = 0; r < 4; ++r)
#pragma unroll
        for (int ct = 0; ct < 4; ++ct) prod[r][ct] = acc[r][ct];
    fusion_pass_pk<513, 16>(apt, wpt, Wt, G, l, acc);
#pragma unroll
    for (int r = 0; r < 4; ++r)
#pragma unroll
        for (int ct = 0; ct < 4; ++ct) prod[r][ct] *= acc[r][ct];
    fusion_pass_pk<513, 16>(apr, wpr, Wr, G, l, acc);
#pragma unroll
    for (int r = 0; r < 4; ++r)
#pragma unroll
        for (int ct = 0; ct < 4; ++ct) prod[r][ct] *= acc[r][ct];

    const float fw0 = fw[0], fw1 = fw[1], fw2 = fw[2], fw3 = fw[3];
#pragma unroll
    for (int ct = 0; ct < 4; ++ct) {
        int c = ct * 16 + (l & 15);
        float fbc = fb[c];
#pragma unroll
        for (int q = 0; q < 4; ++q) {
            int n = G * 16 + (l >> 4) * 4 + q;
            float v = fbc + fw0 * prod[0][ct][q] + fw1 * prod[1][ct][q]
                          + fw2 * prod[2][ct][q] + fw3 * prod[3][ct][q];
            v = v > 0.f ? v : expm1f(v);
            h0b[(size_t)n * 64 + c] = f2b(v);
        }
    }
}

// ---------------------------------------------------------------------------
// feat GEMM (unchanged round-6 structure): 64-node tile, dbuf LDS, 1 barrier
// per chunk. A bf16 via gld_lds16 w/ slot swizzle; B packed fragment-order.
// ---------------------------------------------------------------------------
template<int KT, int NKC>
__device__ __forceinline__ void mm_pass(
    const unsigned short* __restrict__ F, const unsigned short* __restrict__ wp,
    int nb, int w, int l, unsigned short* ldsA, unsigned short* ldsB,
    f32x4 (&acc)[4][4])
{
    {
        int u = w * 64 + l;
        int row = u >> 2, sl = u & 3;
        int s = sl ^ ((row >> 1) & 3);
        int n = nb + row; if (n >= NN) n = NN - 1;
        gld_lds16(F + (size_t)n * KT + s * 8, ldsA + w * 512);
#pragma unroll
        for (int i = 0; i < 4; ++i)
            gld_lds16(wp + (size_t)(w * 4 + i) * 512 + l * 8, ldsB + (w * 4 + i) * 512);
    }
    __syncthreads();

    for (int t = 0; t < NKC; ++t) {
        const int cur = t & 1;
        if (t + 1 < NKC) {
            unsigned short* nA = ldsA + (cur ^ 1) * 2048;
            unsigned short* nB = ldsB + (cur ^ 1) * 8192;
            int u = w * 64 + l;
            int row = u >> 2, sl = u & 3;
            int s = sl ^ ((row >> 1) & 3);
            int n = nb + row; if (n >= NN) n = NN - 1;
            gld_lds16(F + (size_t)n * KT + (t + 1) * 32 + s * 8, nA + w * 512);
            const unsigned short* wsrc = wp + (size_t)(t + 1) * 8192;
#pragma unroll
            for (int i = 0; i < 4; ++i)
                gld_lds16(wsrc + (w * 4 + i) * 512 + l * 8, nB + (w * 4 + i) * 512);
        }
        unsigned short* lB = ldsB + cur * 8192;
        unsigned short* lA = ldsA + cur * 2048;
        bf16x8 bfr[4];
#pragma unroll
        for (int i = 0; i < 4; ++i)
            bfr[i] = *(const bf16x8*)(lB + ((w * 4 + i) * 64 + l) * 8);
#pragma unroll
        for (int nf = 0; nf < 4; ++nf) {
            int row = nf * 16 + (l & 15);
            int so = (l >> 4) ^ ((row >> 1) & 3);
            bf16x8 af = *(const bf16x8*)(lA + row * 32 + so * 8);
#pragma unroll
            for (int i = 0; i < 4; ++i)
                acc[i][nf] = __builtin_amdgcn_mfma_f32_16x16x32_bf16(af, bfr[i], acc[i][nf], 0, 0, 0);
        }
        __syncthreads();
    }
}

template<int K>
__global__ __launch_bounds__(256) void gemm_mfma(
    const unsigned short* __restrict__ Ab, const unsigned short* __restrict__ wp,
    unsigned short* __restrict__ featb)
{
    __shared__ unsigned short ldsA[4096];    // 2 x 4KB
    __shared__ unsigned short ldsB[16384];   // 2 x 16KB
    const int tid = threadIdx.x, w = tid >> 6, l = tid & 63;
    const int nb = blockIdx.x * 64;

    f32x4 acc[4][4];
#pragma unroll
    for (int i = 0; i < 4; ++i)
#pragma unroll
        for (int nf = 0; nf < 4; ++nf) acc[i][nf] = f32x4{0.f, 0.f, 0.f, 0.f};

    mm_pass<K, K / 32>(Ab, wp, nb, w, l, ldsA, ldsB, acc);

#pragma unroll
    for (int i = 0; i < 4; ++i) {
        int c = (w * 4 + i) * 16 + (l & 15);
#pragma unroll
        for (int nf = 0; nf < 4; ++nf)
#pragma unroll
            for (int q = 0; q < 4; ++q) {
                int n = nb + nf * 16 + (l >> 4) * 4 + q;
                if (n < NN) featb[(size_t)n * 256 + c] = f2b(acc[i][nf][q]);
            }
    }
}

// ---------------------------------------------------------------------------
// el/er: one wave per node, bf16 feat input.
// ---------------------------------------------------------------------------
__global__ __launch_bounds__(256) void elr_kernel(
    const unsigned short* __restrict__ featb,
    const float* __restrict__ al, const float* __restrict__ ar,
    float* __restrict__ el, float* __restrict__ er)
{
    int wid = (int)((blockIdx.x * (size_t)blockDim.x + threadIdx.x) >> 6);
    int lane = threadIdx.x & 63;
    if (wid >= NN) return;
    float elh[4], erh[4];
#pragma unroll
    for (int h = 0; h < 4; ++h) {
        float x = b2f(featb[(size_t)wid * 256 + h * 64 + lane]);
        elh[h] = x * al[h * 64 + lane];
        erh[h] = x * ar[h * 64 + lane];
    }
#pragma unroll
    for (int off = 32; off; off >>= 1) {
#pragma unroll
        for (int h = 0; h < 4; ++h) {
            elh[h] += __shfl_xor(elh[h], off);
            erh[h] += __shfl_xor(erh[h], off);
        }
    }
    if (lane == 0) {
        *(float4*)(el + (size_t)wid * 4) = make_float4(elh[0], elh[1], elh[2], elh[3]);
        *(float4*)(er + (size_t)wid * 4) = make_float4(erh[0], erh[1], erh[2], erh[3]);
    }
}

// ---------------------------------------------------------------------------
// CSR build
// ---------------------------------------------------------------------------
__global__ void hist_kernel(const int* __restrict__ dst, int* __restrict__ cnt)
{
    int e = blockIdx.x * blockDim.x + threadIdx.x;
    if (e < EE) atomicAdd(&cnt[dst[e]], 1);
}

__global__ __launch_bounds__(1024) void scan_kernel(const int* __restrict__ cnt, int* __restrict__ offs)
{
    __shared__ int tmp[1024];
    const int t = threadIdx.x;
    const int C = (NN + 1023) / 1024;
    int lo = t * C, hi = min(lo + C, NN);
    int s = 0;
    for (int i = lo; i < hi; ++i) s += cnt[i];
    tmp[t] = s;
    __syncthreads();
    for (int off = 1; off < 1024; off <<= 1) {
        int v = (t >= off) ? tmp[t - off] : 0;
        __syncthreads();
        tmp[t] += v;
        __syncthreads();
    }
    int run = (t == 0) ? 0 : tmp[t - 1];
    for (int i = lo; i < hi; ++i) { offs[i] = run; run += cnt[i]; }
    if (t == 1023) offs[NN] = tmp[1023];
}

__global__ void scatter_kernel(const int* __restrict__ dst, const int* __restrict__ offs,
                               int* __restrict__ cur, int* __restrict__ esort)
{
    int e = blockIdx.x * blockDim.x + threadIdx.x;
    if (e < EE) {
        int d = dst[e];
        int p = offs[d] + atomicAdd(&cur[d], 1);
        esort[p] = e;
    }
}

// ---------------------------------------------------------------------------
// edge_prep: CSR-ordered logits eesort[p] = lrelu(el[src[e]] + er[dst[e]]).
// ---------------------------------------------------------------------------
__global__ void edge_prep(const int* __restrict__ esort, const int* __restrict__ src,
                          const int* __restrict__ dst,
                          const float* __restrict__ el, const float* __restrict__ er,
                          float4* __restrict__ eesort)
{
    int p = blockIdx.x * blockDim.x + threadIdx.x;
    if (p >= EE) return;
    int e = esort[p];
    int s = src[e], d = dst[e];
    float4 l4 = *(const float4*)(el + (size_t)s * 4);
    float4 r4 = *(const float4*)(er + (size_t)d * 4);
    eesort[p] = make_float4(lrelu(l4.x + r4.x), lrelu(l4.y + r4.y),
                            lrelu(l4.z + r4.z), lrelu(l4.w + r4.w));
}

// ---------------------------------------------------------------------------
// Per-dst softmax + aggregation, coalesced logit stream. One wave per node.
// ---------------------------------------------------------------------------
template <int RESID, int WMZ, int WB16>
__global__ __launch_bounds__(256) void gat_agg(
    const int* __restrict__ esort, const int* __restrict__ src, const int* __restrict__ offs,
    const unsigned short* __restrict__ featb, const float4* __restrict__ eesort,
    const float* __restrict__ resid, const float* __restrict__ bias,
    float* __restrict__ out, unsigned short* __restrict__ outb,
    float4* __restrict__ mbuf, float4* __restrict__ zbuf)
{
    int n = (int)((blockIdx.x * (size_t)blockDim.x + threadIdx.x) >> 6);
    int lane = threadIdx.x & 63;
    if (n >= NN) return;
    int s0 = offs[n], s1 = offs[n + 1];

    float m0 = -1e30f, m1 = -1e30f, m2 = -1e30f, m3 = -1e30f;
    for (int p = s0 + lane; p < s1; p += 64) {
        float4 v = eesort[p];
        m0 = fmaxf(m0, v.x); m1 = fmaxf(m1, v.y);
        m2 = fmaxf(m2, v.z); m3 = fmaxf(m3, v.w);
    }
#pragma unroll
    for (int off = 32; off; off >>= 1) {
        m0 = fmaxf(m0, __shfl_xor(m0, off));
        m1 = fmaxf(m1, __shfl_xor(m1, off));
        m2 = fmaxf(m2, __shfl_xor(m2, off));
        m3 = fmaxf(m3, __shfl_xor(m3, off));
    }

    float z0 = 0.f, z1 = 0.f, z2 = 0.f, z3 = 0.f;
    for (int p = s0 + lane; p < s1; p += 64) {
        float4 v = eesort[p];
        z0 += expf(v.x - m0); z1 += expf(v.y - m1);
        z2 += expf(v.z - m2); z3 += expf(v.w - m3);
    }
#pragma unroll
    for (int off = 32; off; off >>= 1) {
        z0 += __shfl_xor(z0, off);
        z1 += __shfl_xor(z1, off);
        z2 += __shfl_xor(z2, off);
        z3 += __shfl_xor(z3, off);
    }
    float i0 = z0 > 0.f ? 1.f / z0 : 0.f;
    float i1 = z1 > 0.f ? 1.f / z1 : 0.f;
    float i2 = z2 > 0.f ? 1.f / z2 : 0.f;
    float i3 = z3 > 0.f ? 1.f / z3 : 0.f;
    if (WMZ && lane == 0) {
        mbuf[n] = make_float4(m0, m1, m2, m3);
        zbuf[n] = make_float4(i0, i1, i2, i3);
    }

    float a0 = 0.f, a1 = 0.f, a2 = 0.f, a3 = 0.f;
    float c0 = 0.f, c1 = 0.f, c2 = 0.f, c3 = 0.f;
    int p = s0;
    for (; p + 1 < s1; p += 2) {
        float4 vA = eesort[p], vB = eesort[p + 1];
        int sA = src[esort[p]], sB = src[esort[p + 1]];
        const unsigned short* fA = featb + (size_t)sA * 256;
        const unsigned short* fB = featb + (size_t)sB * 256;
        float wA0 = expf(vA.x - m0) * i0, wB0 = expf(vB.x - m0) * i0;
        float wA1 = expf(vA.y - m1) * i1, wB1 = expf(vB.y - m1) * i1;
        float wA2 = expf(vA.z - m2) * i2, wB2 = expf(vB.z - m2) * i2;
        float wA3 = expf(vA.w - m3) * i3, wB3 = expf(vB.w - m3) * i3;
        a0 += wA0 * b2f(fA[lane]);        c0 += wB0 * b2f(fB[lane]);
        a1 += wA1 * b2f(fA[64 + lane]);   c1 += wB1 * b2f(fB[64 + lane]);
        a2 += wA2 * b2f(fA[128 + lane]);  c2 += wB2 * b2f(fB[128 + lane]);
        a3 += wA3 * b2f(fA[192 + lane]);  c3 += wB3 * b2f(fB[192 + lane]);
    }
    if (p < s1) {
        float4 v = eesort[p];
        int s = src[esort[p]];
        const unsigned short* fp = featb + (size_t)s * 256;
        a0 += expf(v.x - m0) * i0 * b2f(fp[lane]);
        a1 += expf(v.y - m1) * i1 * b2f(fp[64 + lane]);
        a2 += expf(v.z - m2) * i2 * b2f(fp[128 + lane]);
        a3 += expf(v.w - m3) * i3 * b2f(fp[192 + lane]);
    }
    a0 += c0; a1 += c1; a2 += c2; a3 += c3;

    float o0 = a0 + bias[lane];
    float o1 = a1 + bias[64 + lane];
    float o2 = a2 + bias[128 + lane];
    float o3 = a3 + bias[192 + lane];
    if (RESID) {
        const float* rp = resid + (size_t)n * 256;
        o0 += rp[lane];
        o1 += rp[64 + lane];
        o2 += rp[128 + lane];
        o3 += rp[192 + lane];
    }
    float* op = out + (size_t)n * 256;
    op[lane] = o0;
    op[64 + lane] = o1;
    op[128 + lane] = o2;
    op[192 + lane] = o3;
    if (WB16) {
        unsigned short* ob = outb + (size_t)n * 256;
        ob[lane] = f2b(o0);
        ob[64 + lane] = f2b(o1);
        ob[128 + lane] = f2b(o2);
        ob[192 + lane] = f2b(o3);
    }
}

// ---------------------------------------------------------------------------
// att_final: att[e] = exp(lrelu(el[src]+er[dst]) - m[dst]) / z[dst]
// ---------------------------------------------------------------------------
__global__ void att_final(const int* __restrict__ src, const int* __restrict__ dst,
                          const float* __restrict__ el, const float* __restrict__ er,
                          const float4* __restrict__ mbuf, const float4* __restrict__ zbuf,
                          float4* __restrict__ att)
{
    int e = blockIdx.x * blockDim.x + threadIdx.x;
    if (e >= EE) return;
    int s = src[e], d = dst[e];
    float4 l4 = *(const float4*)(el + (size_t)s * 4);
    float4 r4 = *(const float4*)(er + (size_t)d * 4);
    float4 m4 = mbuf[d], zi = zbuf[d];
    att[e] = make_float4(expf(lrelu(l4.x + r4.x) - m4.x) * zi.x,
                         expf(lrelu(l4.y + r4.y) - m4.y) * zi.y,
                         expf(lrelu(l4.z + r4.z) - m4.z) * zi.z,
                         expf(lrelu(l4.w + r4.w) - m4.w) * zi.w);
}

// ---------------------------------------------------------------------------
extern "C" void kernel_launch(void* const* d_in, const int* in_sizes, int n_in,
                              void* d_out, int out_size, void* d_ws, size_t ws_size,
                              hipStream_t stream)
{
    const int*   src = (const int*)d_in[0];
    const int*   dst = (const int*)d_in[1];
    const float* hc  = (const float*)d_in[2];
    const float* ht  = (const float*)d_in[3];
    const float* hr  = (const float*)d_in[4];
    const float* Wc  = (const float*)d_in[5];
    const float* Wt  = (const float*)d_in[6];
    const float* Wr  = (const float*)d_in[7];
    const float* fw  = (const float*)d_in[8];
    const float* fb  = (const float*)d_in[9];
    const float* W0  = (const float*)d_in[10];
    const float* al0 = (const float*)d_in[11];
    const float* ar0 = (const float*)d_in[12];
    const float* b0  = (const float*)d_in[13];
    const float* W1  = (const float*)d_in[14];
    const float* al1 = (const float*)d_in[15];
    const float* ar1 = (const float*)d_in[16];
    const float* b1  = (const float*)d_in[17];

    // workspace layout (bytes) — unchanged (known-fit)
    char* ws = (char*)d_ws;
    unsigned short* h0b   = (unsigned short*)(ws);               // N*64  bf16 :  6,400,000
    unsigned short* h1b   = (unsigned short*)(ws + 6400000);     // N*256 bf16 : 25,600,000
    unsigned short* featb = (unsigned short*)(ws + 32000000);    // N*256 bf16 : 25,600,000
    float* el    = (float*)(ws + 57600000);                      //    800,000
    float* er    = (float*)(ws + 58400000);                      //    800,000
    int*   cnt   = (int*)  (ws + 59200000);                      //    200,000
    int*   offs  = (int*)  (ws + 59400000);                      //    200,064 (padded)
    int*   esort = (int*)  (ws + 59600128);                      //  3,200,000
    unsigned short* wpc = (unsigned short*)(ws + 62800128);      //  4*16KB =  65,536
    unsigned short* wpt = (unsigned short*)(ws + 62865664);      // 16*16KB = 262,144
    unsigned short* wpr = (unsigned short*)(ws + 63127808);      // 16*16KB = 262,144
    unsigned short* wp0 = (unsigned short*)(ws + 63389952);      //  2*16KB =  32,768
    unsigned short* wp1 = (unsigned short*)(ws + 63422720);      //  8*16KB = 131,072
    float4* mbuf = (float4*)(ws + 63553792);                     //    800,000
    float4* zbuf = (float4*)(ws + 64353792);                     //    800,000
    if (ws_size < 65153792ull) return;                           // end of layout

    float* outh = (float*)d_out;                       // N*256 final h
    float4* atto = (float4*)(outh + (size_t)NN * 256); // E*4 att region

    // A-pack overlays (live only during fusion; consumed before regions are
    // rewritten):  apt -> d_out h-region (51.2MB), apc -> d_out att region
    // (12.8MB), apr -> ws h1b+featb (51.2MB).
    unsigned short* apt = (unsigned short*)d_out;                    // 3125*16*64*8*2 = 51,200,000
    unsigned short* apc = (unsigned short*)((char*)d_out + 51200000); // 3125*4*64*8*2 = 12,800,000
    unsigned short* apr = (unsigned short*)(ws + 6400000);           // 51,200,000

    // weight packing (fragment-order bf16; fusion packs exclude the ones-row)
    pack_w_fusion<<<(4 * 16 * 64 + 255) / 256, 256, 0, stream>>>(Wc, wpc, 129, 4);
    pack_w_fusion<<<(16 * 16 * 64 + 255) / 256, 256, 0, stream>>>(Wt, wpt, 513, 16);
    pack_w_fusion<<<(16 * 16 * 64 + 255) / 256, 256, 0, stream>>>(Wr, wpr, 513, 16);
    pack_w_gemm<<<(2 * 16 * 64 + 255) / 256, 256, 0, stream>>>(W0, wp0, 64, 256);
    pack_w_gemm<<<(8 * 16 * 64 + 255) / 256, 256, 0, stream>>>(W1, wp1, 256, 256);

    // F1: feature packs (f32 -> bf16 A-fragment order)
    pack_a<129, 4><<<NN / 16, 256, 0, stream>>>(hc, apc);
    pack_a<513, 16><<<NN / 16, 256, 0, stream>>>(ht, apt);
    pack_a<513, 16><<<NN / 16, 256, 0, stream>>>(hr, apr);

    // F2: trilinear fusion (barrier-free, LDS-free MFMA)
    fusion_mfma<<<(NN / 16 + 3) / 4, 256, 0, stream>>>(apc, apt, apr, wpc, wpt, wpr,
                                                       Wc, Wt, Wr, fw, fb, h0b);

    // CSR by dst
    hipMemsetAsync(cnt, 0, NN * sizeof(int), stream);
    hist_kernel<<<(EE + 255) / 256, 256, 0, stream>>>(dst, cnt);
    scan_kernel<<<1, 1024, 0, stream>>>(cnt, offs);
    hipMemsetAsync(cnt, 0, NN * sizeof(int), stream);
    scatter_kernel<<<(EE + 255) / 256, 256, 0, stream>>>(dst, offs, cnt, esort);

    // GAT layer 0 (writes outh + h1b, consuming apt/apr regions after fusion)
    gemm_mfma<64><<<(NN + 63) / 64, 256, 0, stream>>>(h0b, wp0, featb);
    elr_kernel<<<(NN * 64 + 255) / 256, 256, 0, stream>>>(featb, al0, ar0, el, er);
    edge_prep<<<(EE + 255) / 256, 256, 0, stream>>>(esort, src, dst, el, er, atto);
    gat_agg<0, 0, 1><<<(NN * 64 + 255) / 256, 256, 0, stream>>>(
        esort, src, offs, featb, atto, nullptr, b0, outh, h1b, nullptr, nullptr);

    // GAT layer 1
    gemm_mfma<256><<<(NN + 63) / 64, 256, 0, stream>>>(h1b, wp1, featb);
    elr_kernel<<<(NN * 64 + 255) / 256, 256, 0, stream>>>(featb, al1, ar1, el, er);
    edge_prep<<<(EE + 255) / 256, 256, 0, stream>>>(esort, src, dst, el, er, atto);
    gat_agg<1, 1, 0><<<(NN * 64 + 255) / 256, 256, 0, stream>>>(
        esort, src, offs, featb, atto, outh, b1, outh, nullptr, mbuf, zbuf);
    att_final<<<(EE + 255) / 256, 256, 0, stream>>>(src, dst, el, er, mbuf, zbuf, atto);
}

// Round 8
// 733.122 us; speedup vs baseline: 1.2800x; 1.2800x over previous
//
#include <hip/hip_runtime.h>
#include <math.h>

#define NN 50000
#define EE 800000
#define NEG 0.2f

using f32x4  = __attribute__((ext_vector_type(4))) float;
using bf16x8 = __attribute__((ext_vector_type(8))) short;

__device__ __forceinline__ float lrelu(float x){ return x > 0.f ? x : NEG*x; }

__device__ __forceinline__ unsigned short f2b(float f){
    unsigned int u = __float_as_uint(f);
    return (unsigned short)((u + 0x7FFFu + ((u >> 16) & 1u)) >> 16);  // RNE
}
__device__ __forceinline__ float b2f(unsigned short h){
    return __uint_as_float(((unsigned int)h) << 16);
}

// ---------------------------------------------------------------------------
// Weight packers (fragment-order bf16).
// Fusion: chunk = ct*4 + r. k < K-1 only (ones-row handled via acc init).
// ---------------------------------------------------------------------------
__global__ void pack_w_fusion(const float* __restrict__ W, unsigned short* __restrict__ out,
                              int K, int NKC)
{
    int u = blockIdx.x * blockDim.x + threadIdx.x;
    if (u >= NKC * 16 * 64) return;
    int l = u & 63, chunk = (u >> 6) & 15, kc = u >> 10;
    int ct = chunk >> 2, r = chunk & 3;
    int c = ct * 16 + (l & 15);
    int kb = kc * 32 + (l >> 4) * 8;
    bf16x8 v;
#pragma unroll
    for (int j = 0; j < 8; ++j)
        v[j] = (short)f2b(W[((size_t)r * K + kb + j) * 64 + c]);
    *(bf16x8*)(out + (size_t)u * 8) = v;
}

// GEMM weights: chunk = ct (C/16 chunks per kc); K multiple of 32.
__global__ void pack_w_gemm(const float* __restrict__ W, unsigned short* __restrict__ out,
                            int K, int C)
{
    int NCH = C / 16;
    int total = (K / 32) * NCH * 64;
    int u = blockIdx.x * blockDim.x + threadIdx.x;
    if (u >= total) return;
    int l = u & 63, ch = (u >> 6) % NCH, kc = u / (64 * NCH);
    int c = ch * 16 + (l & 15);
    int kb = kc * 32 + (l >> 4) * 8;
    bf16x8 v;
#pragma unroll
    for (int j = 0; j < 8; ++j)
        v[j] = (short)f2b(W[(size_t)(kb + j) * C + c]);
    *(bf16x8*)(out + (size_t)u * 8) = v;
}

// ---------------------------------------------------------------------------
// pack_a: f32 features -> bf16 A-fragment order [group][kc][lane][8]
//   node = g*16 + (l&15), k = kc*32 + (l>>4)*8 + j   (k < K-1 only)
// ---------------------------------------------------------------------------
template<int K, int NKC>
__global__ __launch_bounds__(256) void pack_a(
    const float* __restrict__ F, unsigned short* __restrict__ out)
{
    __shared__ float sf[16][K + 3];
    const int tid = threadIdx.x;
    const int g = blockIdx.x, nb = g * 16;

    for (int idx = tid; idx < 16 * K; idx += 256) {
        int row = idx / K, k = idx - row * K;
        sf[row][k] = F[(size_t)(nb + row) * K + k];
    }
    __syncthreads();

    for (int v = tid; v < NKC * 64; v += 256) {
        int kc = v >> 6, l = v & 63;
        int row = l & 15, kb = kc * 32 + (l >> 4) * 8;
        bf16x8 o;
#pragma unroll
        for (int j = 0; j < 8; ++j) o[j] = (short)f2b(sf[row][kb + j]);
        *(bf16x8*)(out + ((size_t)(g * NKC + kc) * 64 + l) * 8) = o;
    }
}

// ---------------------------------------------------------------------------
// Fusion, rank-split: block = 4 waves on one 16-node group; wave w = rank w.
// Per chunk: 1 A-frag (shared addresses across waves -> L1) + 4 B-frags + 4
// MFMA. Tiny register state -> deep compiler prefetch + high occupancy.
// acc initialized from the ones-row W[w][K-1][c] (exact f32).
// ---------------------------------------------------------------------------
template<int K, int NKC>
__device__ __forceinline__ void fusion_pass_rank(
    const unsigned short* __restrict__ ap, const unsigned short* __restrict__ wp,
    const float* __restrict__ W, int G, int w, int l, f32x4 (&acc)[4])
{
    const int c_lo = l & 15;
#pragma unroll
    for (int ct = 0; ct < 4; ++ct) {
        float wi = W[((size_t)w * K + (K - 1)) * 64 + ct * 16 + c_lo];
        acc[ct] = f32x4{wi, wi, wi, wi};
    }
    const unsigned short* abase = ap + (size_t)G * NKC * 512 + l * 8;
#pragma unroll
    for (int kc = 0; kc < NKC; ++kc) {
        bf16x8 af = *(const bf16x8*)(abase + kc * 512);
        const unsigned short* wk = wp + (size_t)kc * 8192 + w * 512 + l * 8;
#pragma unroll
        for (int ct = 0; ct < 4; ++ct) {
            bf16x8 bf = *(const bf16x8*)(wk + ct * 2048);   // chunk = ct*4 + w
            acc[ct] = __builtin_amdgcn_mfma_f32_16x16x32_bf16(af, bf, acc[ct], 0, 0, 0);
        }
    }
}

__global__ __launch_bounds__(256) void fusion_mfma(
    const unsigned short* __restrict__ apc, const unsigned short* __restrict__ apt,
    const unsigned short* __restrict__ apr,
    const unsigned short* __restrict__ wpc, const unsigned short* __restrict__ wpt,
    const unsigned short* __restrict__ wpr,
    const float* __restrict__ Wc, const float* __restrict__ Wt, const float* __restrict__ Wr,
    const float* __restrict__ fw, const float* __restrict__ fb,
    unsigned short* __restrict__ h0b)
{
    __shared__ float lds[4096];   // [r][ct][lane][4] = 16KB
    const int w = threadIdx.x >> 6, l = threadIdx.x & 63;
    const int G = blockIdx.x;

    f32x4 prod[4], acc[4];
    fusion_pass_rank<129, 4>(apc, wpc, Wc, G, w, l, acc);
#pragma unroll
    for (int ct = 0; ct < 4; ++ct) prod[ct] = acc[ct];
    fusion_pass_rank<513, 16>(apt, wpt, Wt, G, w, l, acc);
#pragma unroll
    for (int ct = 0; ct < 4; ++ct) prod[ct] *= acc[ct];
    fusion_pass_rank<513, 16>(apr, wpr, Wr, G, w, l, acc);
    const float fww = fw[w];
#pragma unroll
    for (int ct = 0; ct < 4; ++ct) {
        prod[ct] *= acc[ct];
        *(f32x4*)&lds[((w * 4 + ct) * 64 + l) * 4] = prod[ct] * fww;
    }
    __syncthreads();

    // wave w sums the 4 ranks for col-tile ct = w
    f32x4 s = *(const f32x4*)&lds[((0 * 4 + w) * 64 + l) * 4];
#pragma unroll
    for (int r = 1; r < 4; ++r)
        s += *(const f32x4*)&lds[((r * 4 + w) * 64 + l) * 4];

    const int c = w * 16 + (l & 15);
    const float fbc = fb[c];
#pragma unroll
    for (int q = 0; q < 4; ++q) {
        int n = G * 16 + (l >> 4) * 4 + q;
        float v = s[q] + fbc;
        v = v > 0.f ? v : expm1f(v);
        h0b[(size_t)n * 64 + c] = f2b(v);
    }
}

// ---------------------------------------------------------------------------
// feat GEMM, register-streaming: block = 4 waves on one 16-node group;
// wave w owns cols [64w, 64w+64). Per chunk: 1 A-frag + 4 B-frags + 4 MFMA.
// ---------------------------------------------------------------------------
template<int K>
__global__ __launch_bounds__(256) void gemm_reg(
    const unsigned short* __restrict__ Ab, const unsigned short* __restrict__ wp,
    unsigned short* __restrict__ featb)
{
    constexpr int NKC = K / 32;
    const int w = threadIdx.x >> 6, l = threadIdx.x & 63;
    const int nb = blockIdx.x * 16;

    f32x4 acc[4];
#pragma unroll
    for (int i = 0; i < 4; ++i) acc[i] = f32x4{0.f, 0.f, 0.f, 0.f};

    const unsigned short* abase = Ab + (size_t)(nb + (l & 15)) * K + (l >> 4) * 8;
#pragma unroll
    for (int kc = 0; kc < NKC; ++kc) {
        bf16x8 af = *(const bf16x8*)(abase + kc * 32);
        const unsigned short* wk = wp + ((size_t)kc * 16 + w * 4) * 512 + l * 8;
#pragma unroll
        for (int i = 0; i < 4; ++i) {
            bf16x8 bf = *(const bf16x8*)(wk + i * 512);
            acc[i] = __builtin_amdgcn_mfma_f32_16x16x32_bf16(af, bf, acc[i], 0, 0, 0);
        }
    }
#pragma unroll
    for (int i = 0; i < 4; ++i) {
        int c = (w * 4 + i) * 16 + (l & 15);
#pragma unroll
        for (int q = 0; q < 4; ++q) {
            int n = nb + (l >> 4) * 4 + q;
            featb[(size_t)n * 256 + c] = f2b(acc[i][q]);
        }
    }
}

// ---------------------------------------------------------------------------
// el/er: one wave per node, bf16 feat input.
// ---------------------------------------------------------------------------
__global__ __launch_bounds__(256) void elr_kernel(
    const unsigned short* __restrict__ featb,
    const float* __restrict__ al, const float* __restrict__ ar,
    float* __restrict__ el, float* __restrict__ er)
{
    int wid = (int)((blockIdx.x * (size_t)blockDim.x + threadIdx.x) >> 6);
    int lane = threadIdx.x & 63;
    if (wid >= NN) return;
    float elh[4], erh[4];
#pragma unroll
    for (int h = 0; h < 4; ++h) {
        float x = b2f(featb[(size_t)wid * 256 + h * 64 + lane]);
        elh[h] = x * al[h * 64 + lane];
        erh[h] = x * ar[h * 64 + lane];
    }
#pragma unroll
    for (int off = 32; off; off >>= 1) {
#pragma unroll
        for (int h = 0; h < 4; ++h) {
            elh[h] += __shfl_xor(elh[h], off);
            erh[h] += __shfl_xor(erh[h], off);
        }
    }
    if (lane == 0) {
        *(float4*)(el + (size_t)wid * 4) = make_float4(elh[0], elh[1], elh[2], elh[3]);
        *(float4*)(er + (size_t)wid * 4) = make_float4(erh[0], erh[1], erh[2], erh[3]);
    }
}

// ---------------------------------------------------------------------------
// CSR build
// ---------------------------------------------------------------------------
__global__ void hist_kernel(const int* __restrict__ dst, int* __restrict__ cnt)
{
    int e = blockIdx.x * blockDim.x + threadIdx.x;
    if (e < EE) atomicAdd(&cnt[dst[e]], 1);
}

__global__ __launch_bounds__(1024) void scan_kernel(const int* __restrict__ cnt, int* __restrict__ offs)
{
    __shared__ int tmp[1024];
    const int t = threadIdx.x;
    const int C = (NN + 1023) / 1024;
    int lo = t * C, hi = min(lo + C, NN);
    int s = 0;
    for (int i = lo; i < hi; ++i) s += cnt[i];
    tmp[t] = s;
    __syncthreads();
    for (int off = 1; off < 1024; off <<= 1) {
        int v = (t >= off) ? tmp[t - off] : 0;
        __syncthreads();
        tmp[t] += v;
        __syncthreads();
    }
    int run = (t == 0) ? 0 : tmp[t - 1];
    for (int i = lo; i < hi; ++i) { offs[i] = run; run += cnt[i]; }
    if (t == 1023) offs[NN] = tmp[1023];
}

__global__ void scatter_kernel(const int* __restrict__ dst, const int* __restrict__ offs,
                               int* __restrict__ cur, int* __restrict__ esort)
{
    int e = blockIdx.x * blockDim.x + threadIdx.x;
    if (e < EE) {
        int d = dst[e];
        int p = offs[d] + atomicAdd(&cur[d], 1);
        esort[p] = e;
    }
}

// ---------------------------------------------------------------------------
// edge_prep: CSR-ordered logits eesort[p] = lrelu(el[src[e]] + er[dst[e]]).
// ---------------------------------------------------------------------------
__global__ void edge_prep(const int* __restrict__ esort, const int* __restrict__ src,
                          const int* __restrict__ dst,
                          const float* __restrict__ el, const float* __restrict__ er,
                          float4* __restrict__ eesort)
{
    int p = blockIdx.x * blockDim.x + threadIdx.x;
    if (p >= EE) return;
    int e = esort[p];
    int s = src[e], d = dst[e];
    float4 l4 = *(const float4*)(el + (size_t)s * 4);
    float4 r4 = *(const float4*)(er + (size_t)d * 4);
    eesort[p] = make_float4(lrelu(l4.x + r4.x), lrelu(l4.y + r4.y),
                            lrelu(l4.z + r4.z), lrelu(l4.w + r4.w));
}

// ---------------------------------------------------------------------------
// Per-dst softmax + aggregation, coalesced logit stream. One wave per node.
// ---------------------------------------------------------------------------
template <int RESID, int WMZ, int WB16>
__global__ __launch_bounds__(256) void gat_agg(
    const int* __restrict__ esort, const int* __restrict__ src, const int* __restrict__ offs,
    const unsigned short* __restrict__ featb, const float4* __restrict__ eesort,
    const float* __restrict__ resid, const float* __restrict__ bias,
    float* __restrict__ out, unsigned short* __restrict__ outb,
    float4* __restrict__ mbuf, float4* __restrict__ zbuf)
{
    int n = (int)((blockIdx.x * (size_t)blockDim.x + threadIdx.x) >> 6);
    int lane = threadIdx.x & 63;
    if (n >= NN) return;
    int s0 = offs[n], s1 = offs[n + 1];

    float m0 = -1e30f, m1 = -1e30f, m2 = -1e30f, m3 = -1e30f;
    for (int p = s0 + lane; p < s1; p += 64) {
        float4 v = eesort[p];
        m0 = fmaxf(m0, v.x); m1 = fmaxf(m1, v.y);
        m2 = fmaxf(m2, v.z); m3 = fmaxf(m3, v.w);
    }
#pragma unroll
    for (int off = 32; off; off >>= 1) {
        m0 = fmaxf(m0, __shfl_xor(m0, off));
        m1 = fmaxf(m1, __shfl_xor(m1, off));
        m2 = fmaxf(m2, __shfl_xor(m2, off));
        m3 = fmaxf(m3, __shfl_xor(m3, off));
    }

    float z0 = 0.f, z1 = 0.f, z2 = 0.f, z3 = 0.f;
    for (int p = s0 + lane; p < s1; p += 64) {
        float4 v = eesort[p];
        z0 += expf(v.x - m0); z1 += expf(v.y - m1);
        z2 += expf(v.z - m2); z3 += expf(v.w - m3);
    }
#pragma unroll
    for (int off = 32; off; off >>= 1) {
        z0 += __shfl_xor(z0, off);
        z1 += __shfl_xor(z1, off);
        z2 += __shfl_xor(z2, off);
        z3 += __shfl_xor(z3, off);
    }
    float i0 = z0 > 0.f ? 1.f / z0 : 0.f;
    float i1 = z1 > 0.f ? 1.f / z1 : 0.f;
    float i2 = z2 > 0.f ? 1.f / z2 : 0.f;
    float i3 = z3 > 0.f ? 1.f / z3 : 0.f;
    if (WMZ && lane == 0) {
        mbuf[n] = make_float4(m0, m1, m2, m3);
        zbuf[n] = make_float4(i0, i1, i2, i3);
    }

    float a0 = 0.f, a1 = 0.f, a2 = 0.f, a3 = 0.f;
    float c0 = 0.f, c1 = 0.f, c2 = 0.f, c3 = 0.f;
    int p = s0;
    for (; p + 1 < s1; p += 2) {
        float4 vA = eesort[p], vB = eesort[p + 1];
        int sA = src[esort[p]], sB = src[esort[p + 1]];
        const unsigned short* fA = featb + (size_t)sA * 256;
        const unsigned short* fB = featb + (size_t)sB * 256;
        float wA0 = expf(vA.x - m0) * i0, wB0 = expf(vB.x - m0) * i0;
        float wA1 = expf(vA.y - m1) * i1, wB1 = expf(vB.y - m1) * i1;
        float wA2 = expf(vA.z - m2) * i2, wB2 = expf(vB.z - m2) * i2;
        float wA3 = expf(vA.w - m3) * i3, wB3 = expf(vB.w - m3) * i3;
        a0 += wA0 * b2f(fA[lane]);        c0 += wB0 * b2f(fB[lane]);
        a1 += wA1 * b2f(fA[64 + lane]);   c1 += wB1 * b2f(fB[64 + lane]);
        a2 += wA2 * b2f(fA[128 + lane]);  c2 += wB2 * b2f(fB[128 + lane]);
        a3 += wA3 * b2f(fA[192 + lane]);  c3 += wB3 * b2f(fB[192 + lane]);
    }
    if (p < s1) {
        float4 v = eesort[p];
        int s = src[esort[p]];
        const unsigned short* fp = featb + (size_t)s * 256;
        a0 += expf(v.x - m0) * i0 * b2f(fp[lane]);
        a1 += expf(v.y - m1) * i1 * b2f(fp[64 + lane]);
        a2 += expf(v.z - m2) * i2 * b2f(fp[128 + lane]);
        a3 += expf(v.w - m3) * i3 * b2f(fp[192 + lane]);
    }
    a0 += c0; a1 += c1; a2 += c2; a3 += c3;

    float o0 = a0 + bias[lane];
    float o1 = a1 + bias[64 + lane];
    float o2 = a2 + bias[128 + lane];
    float o3 = a3 + bias[192 + lane];
    if (RESID) {
        const float* rp = resid + (size_t)n * 256;
        o0 += rp[lane];
        o1 += rp[64 + lane];
        o2 += rp[128 + lane];
        o3 += rp[192 + lane];
    }
    float* op = out + (size_t)n * 256;
    op[lane] = o0;
    op[64 + lane] = o1;
    op[128 + lane] = o2;
    op[192 + lane] = o3;
    if (WB16) {
        unsigned short* ob = outb + (size_t)n * 256;
        ob[lane] = f2b(o0);
        ob[64 + lane] = f2b(o1);
        ob[128 + lane] = f2b(o2);
        ob[192 + lane] = f2b(o3);
    }
}

// ---------------------------------------------------------------------------
// att_final: att[e] = exp(lrelu(el[src]+er[dst]) - m[dst]) / z[dst]
// ---------------------------------------------------------------------------
__global__ void att_final(const int* __restrict__ src, const int* __restrict__ dst,
                          const float* __restrict__ el, const float* __restrict__ er,
                          const float4* __restrict__ mbuf, const float4* __restrict__ zbuf,
                          float4* __restrict__ att)
{
    int e = blockIdx.x * blockDim.x + threadIdx.x;
    if (e >= EE) return;
    int s = src[e], d = dst[e];
    float4 l4 = *(const float4*)(el + (size_t)s * 4);
    float4 r4 = *(const float4*)(er + (size_t)d * 4);
    float4 m4 = mbuf[d], zi = zbuf[d];
    att[e] = make_float4(expf(lrelu(l4.x + r4.x) - m4.x) * zi.x,
                         expf(lrelu(l4.y + r4.y) - m4.y) * zi.y,
                         expf(lrelu(l4.z + r4.z) - m4.z) * zi.z,
                         expf(lrelu(l4.w + r4.w) - m4.w) * zi.w);
}

// ---------------------------------------------------------------------------
extern "C" void kernel_launch(void* const* d_in, const int* in_sizes, int n_in,
                              void* d_out, int out_size, void* d_ws, size_t ws_size,
                              hipStream_t stream)
{
    const int*   src = (const int*)d_in[0];
    const int*   dst = (const int*)d_in[1];
    const float* hc  = (const float*)d_in[2];
    const float* ht  = (const float*)d_in[3];
    const float* hr  = (const float*)d_in[4];
    const float* Wc  = (const float*)d_in[5];
    const float* Wt  = (const float*)d_in[6];
    const float* Wr  = (const float*)d_in[7];
    const float* fw  = (const float*)d_in[8];
    const float* fb  = (const float*)d_in[9];
    const float* W0  = (const float*)d_in[10];
    const float* al0 = (const float*)d_in[11];
    const float* ar0 = (const float*)d_in[12];
    const float* b0  = (const float*)d_in[13];
    const float* W1  = (const float*)d_in[14];
    const float* al1 = (const float*)d_in[15];
    const float* ar1 = (const float*)d_in[16];
    const float* b1  = (const float*)d_in[17];

    // workspace layout (bytes) — unchanged (known-fit)
    char* ws = (char*)d_ws;
    unsigned short* h0b   = (unsigned short*)(ws);               // N*64  bf16 :  6,400,000
    unsigned short* h1b   = (unsigned short*)(ws + 6400000);     // N*256 bf16 : 25,600,000
    unsigned short* featb = (unsigned short*)(ws + 32000000);    // N*256 bf16 : 25,600,000
    float* el    = (float*)(ws + 57600000);                      //    800,000
    float* er    = (float*)(ws + 58400000);                      //    800,000
    int*   cnt   = (int*)  (ws + 59200000);                      //    200,000
    int*   offs  = (int*)  (ws + 59400000);                      //    200,064 (padded)
    int*   esort = (int*)  (ws + 59600128);                      //  3,200,000
    unsigned short* wpc = (unsigned short*)(ws + 62800128);      //  4*16KB =  65,536
    unsigned short* wpt = (unsigned short*)(ws + 62865664);      // 16*16KB = 262,144
    unsigned short* wpr = (unsigned short*)(ws + 63127808);      // 16*16KB = 262,144
    unsigned short* wp0 = (unsigned short*)(ws + 63389952);      //  2*16KB =  32,768
    unsigned short* wp1 = (unsigned short*)(ws + 63422720);      //  8*16KB = 131,072
    float4* mbuf = (float4*)(ws + 63553792);                     //    800,000
    float4* zbuf = (float4*)(ws + 64353792);                     //    800,000
    if (ws_size < 65153792ull) return;                           // end of layout

    float* outh = (float*)d_out;                       // N*256 final h
    float4* atto = (float4*)(outh + (size_t)NN * 256); // E*4 att region

    // A-pack overlays (live only during fusion; consumed before regions are
    // rewritten):  apt -> d_out h-region (51.2MB), apc -> d_out att region
    // (12.8MB), apr -> ws h1b+featb (51.2MB).
    unsigned short* apt = (unsigned short*)d_out;                     // 51,200,000
    unsigned short* apc = (unsigned short*)((char*)d_out + 51200000); // 12,800,000
    unsigned short* apr = (unsigned short*)(ws + 6400000);            // 51,200,000

    // weight packing (fragment-order bf16; fusion packs exclude the ones-row)
    pack_w_fusion<<<(4 * 16 * 64 + 255) / 256, 256, 0, stream>>>(Wc, wpc, 129, 4);
    pack_w_fusion<<<(16 * 16 * 64 + 255) / 256, 256, 0, stream>>>(Wt, wpt, 513, 16);
    pack_w_fusion<<<(16 * 16 * 64 + 255) / 256, 256, 0, stream>>>(Wr, wpr, 513, 16);
    pack_w_gemm<<<(2 * 16 * 64 + 255) / 256, 256, 0, stream>>>(W0, wp0, 64, 256);
    pack_w_gemm<<<(8 * 16 * 64 + 255) / 256, 256, 0, stream>>>(W1, wp1, 256, 256);

    // F1: feature packs (f32 -> bf16 A-fragment order)
    pack_a<129, 4><<<NN / 16, 256, 0, stream>>>(hc, apc);
    pack_a<513, 16><<<NN / 16, 256, 0, stream>>>(ht, apt);
    pack_a<513, 16><<<NN / 16, 256, 0, stream>>>(hr, apr);

    // F2: trilinear fusion (rank-split register streaming, 1 barrier/block)
    fusion_mfma<<<NN / 16, 256, 0, stream>>>(apc, apt, apr, wpc, wpt, wpr,
                                             Wc, Wt, Wr, fw, fb, h0b);

    // CSR by dst
    hipMemsetAsync(cnt, 0, NN * sizeof(int), stream);
    hist_kernel<<<(EE + 255) / 256, 256, 0, stream>>>(dst, cnt);
    scan_kernel<<<1, 1024, 0, stream>>>(cnt, offs);
    hipMemsetAsync(cnt, 0, NN * sizeof(int), stream);
    scatter_kernel<<<(EE + 255) / 256, 256, 0, stream>>>(dst, offs, cnt, esort);

    // GAT layer 0
    gemm_reg<64><<<NN / 16, 256, 0, stream>>>(h0b, wp0, featb);
    elr_kernel<<<(NN * 64 + 255) / 256, 256, 0, stream>>>(featb, al0, ar0, el, er);
    edge_prep<<<(EE + 255) / 256, 256, 0, stream>>>(esort, src, dst, el, er, atto);
    gat_agg<0, 0, 1><<<(NN * 64 + 255) / 256, 256, 0, stream>>>(
        esort, src, offs, featb, atto, nullptr, b0, outh, h1b, nullptr, nullptr);

    // GAT layer 1
    gemm_reg<256><<<NN / 16, 256, 0, stream>>>(h1b, wp1, featb);
    elr_kernel<<<(NN * 64 + 255) / 256, 256, 0, stream>>>(featb, al1, ar1, el, er);
    edge_prep<<<(EE + 255) / 256, 256, 0, stream>>>(esort, src, dst, el, er, atto);
    gat_agg<1, 1, 0><<<(NN * 64 + 255) / 256, 256, 0, stream>>>(
        esort, src, offs, featb, atto, outh, b1, outh, nullptr, mbuf, zbuf);
    att_final<<<(EE + 255) / 256, 256, 0, stream>>>(src, dst, el, er, mbuf, zbuf, atto);
}

// Round 9
// 660.906 us; speedup vs baseline: 1.4199x; 1.1093x over previous
//
#include <hip/hip_runtime.h>
#include <math.h>

#define NN 50000
#define EE 800000
#define NEG 0.2f

using f32x4  = __attribute__((ext_vector_type(4))) float;
using bf16x8 = __attribute__((ext_vector_type(8))) short;

__device__ __forceinline__ float lrelu(float x){ return x > 0.f ? x : NEG*x; }

__device__ __forceinline__ unsigned short f2b(float f){
    unsigned int u = __float_as_uint(f);
    return (unsigned short)((u + 0x7FFFu + ((u >> 16) & 1u)) >> 16);  // RNE
}
__device__ __forceinline__ float b2f(unsigned short h){
    return __uint_as_float(((unsigned int)h) << 16);
}

// ---------------------------------------------------------------------------
// Weight packers (fragment-order bf16).
// Fusion: chunk = ct*4 + r. k < K-1 only (ones-row handled via acc init).
// ---------------------------------------------------------------------------
__global__ void pack_w_fusion(const float* __restrict__ W, unsigned short* __restrict__ out,
                              int K, int NKC)
{
    int u = blockIdx.x * blockDim.x + threadIdx.x;
    if (u >= NKC * 16 * 64) return;
    int l = u & 63, chunk = (u >> 6) & 15, kc = u >> 10;
    int ct = chunk >> 2, r = chunk & 3;
    int c = ct * 16 + (l & 15);
    int kb = kc * 32 + (l >> 4) * 8;
    bf16x8 v;
#pragma unroll
    for (int j = 0; j < 8; ++j)
        v[j] = (short)f2b(W[((size_t)r * K + kb + j) * 64 + c]);
    *(bf16x8*)(out + (size_t)u * 8) = v;
}

// GEMM weights: chunk = ct (C/16 chunks per kc); K multiple of 32.
// PERM=1: A rows are stored head-minor (k_store = d*4+h <-> k_orig = h*64+d).
template<int PERM>
__global__ void pack_w_gemm(const float* __restrict__ W, unsigned short* __restrict__ out,
                            int K, int C)
{
    int NCH = C / 16;
    int total = (K / 32) * NCH * 64;
    int u = blockIdx.x * blockDim.x + threadIdx.x;
    if (u >= total) return;
    int l = u & 63, ch = (u >> 6) % NCH, kc = u / (64 * NCH);
    int c = ch * 16 + (l & 15);
    int kb = kc * 32 + (l >> 4) * 8;
    bf16x8 v;
#pragma unroll
    for (int j = 0; j < 8; ++j) {
        int k = kb + j;
        int ko = PERM ? ((k & 3) * 64 + (k >> 2)) : k;
        v[j] = (short)f2b(W[(size_t)ko * C + c]);
    }
    *(bf16x8*)(out + (size_t)u * 8) = v;
}

// ---------------------------------------------------------------------------
// pack_a: f32 features -> bf16 A-fragment order [group][kc][lane][8]
// ---------------------------------------------------------------------------
template<int K, int NKC>
__global__ __launch_bounds__(256) void pack_a(
    const float* __restrict__ F, unsigned short* __restrict__ out)
{
    __shared__ float sf[16][K + 3];
    const int tid = threadIdx.x;
    const int g = blockIdx.x, nb = g * 16;

    for (int idx = tid; idx < 16 * K; idx += 256) {
        int row = idx / K, k = idx - row * K;
        sf[row][k] = F[(size_t)(nb + row) * K + k];
    }
    __syncthreads();

    for (int v = tid; v < NKC * 64; v += 256) {
        int kc = v >> 6, l = v & 63;
        int row = l & 15, kb = kc * 32 + (l >> 4) * 8;
        bf16x8 o;
#pragma unroll
        for (int j = 0; j < 8; ++j) o[j] = (short)f2b(sf[row][kb + j]);
        *(bf16x8*)(out + ((size_t)(g * NKC + kc) * 64 + l) * 8) = o;
    }
}

// ---------------------------------------------------------------------------
// Fusion, rank-split: block = 4 waves on one 16-node group; wave w = rank w.
// ---------------------------------------------------------------------------
template<int K, int NKC>
__device__ __forceinline__ void fusion_pass_rank(
    const unsigned short* __restrict__ ap, const unsigned short* __restrict__ wp,
    const float* __restrict__ W, int G, int w, int l, f32x4 (&acc)[4])
{
    const int c_lo = l & 15;
#pragma unroll
    for (int ct = 0; ct < 4; ++ct) {
        float wi = W[((size_t)w * K + (K - 1)) * 64 + ct * 16 + c_lo];
        acc[ct] = f32x4{wi, wi, wi, wi};
    }
    const unsigned short* abase = ap + (size_t)G * NKC * 512 + l * 8;
#pragma unroll
    for (int kc = 0; kc < NKC; ++kc) {
        bf16x8 af = *(const bf16x8*)(abase + kc * 512);
        const unsigned short* wk = wp + (size_t)kc * 8192 + w * 512 + l * 8;
#pragma unroll
        for (int ct = 0; ct < 4; ++ct) {
            bf16x8 bf = *(const bf16x8*)(wk + ct * 2048);   // chunk = ct*4 + w
            acc[ct] = __builtin_amdgcn_mfma_f32_16x16x32_bf16(af, bf, acc[ct], 0, 0, 0);
        }
    }
}

__global__ __launch_bounds__(256) void fusion_mfma(
    const unsigned short* __restrict__ apc, const unsigned short* __restrict__ apt,
    const unsigned short* __restrict__ apr,
    const unsigned short* __restrict__ wpc, const unsigned short* __restrict__ wpt,
    const unsigned short* __restrict__ wpr,
    const float* __restrict__ Wc, const float* __restrict__ Wt, const float* __restrict__ Wr,
    const float* __restrict__ fw, const float* __restrict__ fb,
    unsigned short* __restrict__ h0b)
{
    __shared__ float lds[4096];   // [r][ct][lane][4] = 16KB
    const int w = threadIdx.x >> 6, l = threadIdx.x & 63;
    const int G = blockIdx.x;

    f32x4 prod[4], acc[4];
    fusion_pass_rank<129, 4>(apc, wpc, Wc, G, w, l, acc);
#pragma unroll
    for (int ct = 0; ct < 4; ++ct) prod[ct] = acc[ct];
    fusion_pass_rank<513, 16>(apt, wpt, Wt, G, w, l, acc);
#pragma unroll
    for (int ct = 0; ct < 4; ++ct) prod[ct] *= acc[ct];
    fusion_pass_rank<513, 16>(apr, wpr, Wr, G, w, l, acc);
    const float fww = fw[w];
#pragma unroll
    for (int ct = 0; ct < 4; ++ct) {
        prod[ct] *= acc[ct];
        *(f32x4*)&lds[((w * 4 + ct) * 64 + l) * 4] = prod[ct] * fww;
    }
    __syncthreads();

    f32x4 s = *(const f32x4*)&lds[((0 * 4 + w) * 64 + l) * 4];
#pragma unroll
    for (int r = 1; r < 4; ++r)
        s += *(const f32x4*)&lds[((r * 4 + w) * 64 + l) * 4];

    const int c = w * 16 + (l & 15);
    const float fbc = fb[c];
#pragma unroll
    for (int q = 0; q < 4; ++q) {
        int n = G * 16 + (l >> 4) * 4 + q;
        float v = s[q] + fbc;
        v = v > 0.f ? v : expm1f(v);
        h0b[(size_t)n * 64 + c] = f2b(v);
    }
}

// ---------------------------------------------------------------------------
// feat GEMM, register-streaming. Output stored HEAD-MINOR: featb[n][d*4+h].
// (wave w produces only h = w; d = 16i + (l&15))
// ---------------------------------------------------------------------------
template<int K>
__global__ __launch_bounds__(256) void gemm_reg(
    const unsigned short* __restrict__ Ab, const unsigned short* __restrict__ wp,
    unsigned short* __restrict__ featb)
{
    constexpr int NKC = K / 32;
    const int w = threadIdx.x >> 6, l = threadIdx.x & 63;
    const int nb = blockIdx.x * 16;

    f32x4 acc[4];
#pragma unroll
    for (int i = 0; i < 4; ++i) acc[i] = f32x4{0.f, 0.f, 0.f, 0.f};

    const unsigned short* abase = Ab + (size_t)(nb + (l & 15)) * K + (l >> 4) * 8;
#pragma unroll
    for (int kc = 0; kc < NKC; ++kc) {
        bf16x8 af = *(const bf16x8*)(abase + kc * 32);
        const unsigned short* wk = wp + ((size_t)kc * 16 + w * 4) * 512 + l * 8;
#pragma unroll
        for (int i = 0; i < 4; ++i) {
            bf16x8 bf = *(const bf16x8*)(wk + i * 512);
            acc[i] = __builtin_amdgcn_mfma_f32_16x16x32_bf16(af, bf, acc[i], 0, 0, 0);
        }
    }
#pragma unroll
    for (int i = 0; i < 4; ++i) {
        int c = (w * 4 + i) * 16 + (l & 15);
        int dm = (c & 63) * 4 + (c >> 6);   // head-minor index
#pragma unroll
        for (int q = 0; q < 4; ++q) {
            int n = nb + (l >> 4) * 4 + q;
            featb[(size_t)n * 256 + dm] = f2b(acc[i][q]);
        }
    }
}

// ---------------------------------------------------------------------------
// el/er: one wave per node; head-minor feat -> single ushort4 load per lane.
// ---------------------------------------------------------------------------
__global__ __launch_bounds__(256) void elr_kernel(
    const unsigned short* __restrict__ featb,
    const float* __restrict__ al, const float* __restrict__ ar,
    float* __restrict__ el, float* __restrict__ er)
{
    int wid = (int)((blockIdx.x * (size_t)blockDim.x + threadIdx.x) >> 6);
    int lane = threadIdx.x & 63;
    if (wid >= NN) return;
    ushort4 f4 = *(const ushort4*)(featb + (size_t)wid * 256 + lane * 4);
    float x0 = b2f(f4.x), x1 = b2f(f4.y), x2 = b2f(f4.z), x3 = b2f(f4.w);
    float elh[4], erh[4];
    elh[0] = x0 * al[lane];        erh[0] = x0 * ar[lane];
    elh[1] = x1 * al[64 + lane];   erh[1] = x1 * ar[64 + lane];
    elh[2] = x2 * al[128 + lane];  erh[2] = x2 * ar[128 + lane];
    elh[3] = x3 * al[192 + lane];  erh[3] = x3 * ar[192 + lane];
#pragma unroll
    for (int off = 32; off; off >>= 1) {
#pragma unroll
        for (int h = 0; h < 4; ++h) {
            elh[h] += __shfl_xor(elh[h], off);
            erh[h] += __shfl_xor(erh[h], off);
        }
    }
    if (lane == 0) {
        *(float4*)(el + (size_t)wid * 4) = make_float4(elh[0], elh[1], elh[2], elh[3]);
        *(float4*)(er + (size_t)wid * 4) = make_float4(erh[0], erh[1], erh[2], erh[3]);
    }
}

// ---------------------------------------------------------------------------
// CSR build
// ---------------------------------------------------------------------------
__global__ void hist_kernel(const int* __restrict__ dst, int* __restrict__ cnt)
{
    int e = blockIdx.x * blockDim.x + threadIdx.x;
    if (e < EE) atomicAdd(&cnt[dst[e]], 1);
}

__global__ __launch_bounds__(1024) void scan_kernel(const int* __restrict__ cnt, int* __restrict__ offs)
{
    __shared__ int tmp[1024];
    const int t = threadIdx.x;
    const int C = (NN + 1023) / 1024;
    int lo = t * C, hi = min(lo + C, NN);
    int s = 0;
    for (int i = lo; i < hi; ++i) s += cnt[i];
    tmp[t] = s;
    __syncthreads();
    for (int off = 1; off < 1024; off <<= 1) {
        int v = (t >= off) ? tmp[t - off] : 0;
        __syncthreads();
        tmp[t] += v;
        __syncthreads();
    }
    int run = (t == 0) ? 0 : tmp[t - 1];
    for (int i = lo; i < hi; ++i) { offs[i] = run; run += cnt[i]; }
    if (t == 1023) offs[NN] = tmp[1023];
}

__global__ void scatter_kernel(const int* __restrict__ dst, const int* __restrict__ offs,
                               int* __restrict__ cur, int* __restrict__ esort)
{
    int e = blockIdx.x * blockDim.x + threadIdx.x;
    if (e < EE) {
        int d = dst[e];
        int p = offs[d] + atomicAdd(&cur[d], 1);
        esort[p] = e;
    }
}

// ---------------------------------------------------------------------------
// edge_prep: CSR-ordered logits + CSR-ordered src index.
// ---------------------------------------------------------------------------
__global__ void edge_prep(const int* __restrict__ esort, const int* __restrict__ src,
                          const int* __restrict__ dst,
                          const float* __restrict__ el, const float* __restrict__ er,
                          float4* __restrict__ eesort, int* __restrict__ srcsort)
{
    int p = blockIdx.x * blockDim.x + threadIdx.x;
    if (p >= EE) return;
    int e = esort[p];
    int s = src[e], d = dst[e];
    srcsort[p] = s;
    float4 l4 = *(const float4*)(el + (size_t)s * 4);
    float4 r4 = *(const float4*)(er + (size_t)d * 4);
    eesort[p] = make_float4(lrelu(l4.x + r4.x), lrelu(l4.y + r4.y),
                            lrelu(l4.z + r4.z), lrelu(l4.w + r4.w));
}

// ---------------------------------------------------------------------------
// Per-dst softmax + aggregation. One wave per node.
// Pass A: strided max. Pass B: strided exp(v-m), WRITTEN BACK into eesort,
// z-sum. Pass C: serial edges; weights read ready-made (uniform float4),
// 1/z deferred to epilogue -> per-edge VALU ~= 1 ushort4 load + 4 cvt + 4 fma.
// ---------------------------------------------------------------------------
template <int RESID, int WMZ, int WB16, int WF32>
__global__ __launch_bounds__(256) void gat_agg(
    const int* __restrict__ srcsort, const int* __restrict__ offs,
    const unsigned short* __restrict__ featb, float4* __restrict__ eesort,
    const unsigned short* __restrict__ residb, const float* __restrict__ bias,
    float* __restrict__ out, unsigned short* __restrict__ outb,
    float4* __restrict__ mbuf, float4* __restrict__ zbuf)
{
    int n = (int)((blockIdx.x * (size_t)blockDim.x + threadIdx.x) >> 6);
    int lane = threadIdx.x & 63;
    if (n >= NN) return;
    int s0 = offs[n], s1 = offs[n + 1];

    float m0 = -1e30f, m1 = -1e30f, m2 = -1e30f, m3 = -1e30f;
    for (int p = s0 + lane; p < s1; p += 64) {
        float4 v = eesort[p];
        m0 = fmaxf(m0, v.x); m1 = fmaxf(m1, v.y);
        m2 = fmaxf(m2, v.z); m3 = fmaxf(m3, v.w);
    }
#pragma unroll
    for (int off = 32; off; off >>= 1) {
        m0 = fmaxf(m0, __shfl_xor(m0, off));
        m1 = fmaxf(m1, __shfl_xor(m1, off));
        m2 = fmaxf(m2, __shfl_xor(m2, off));
        m3 = fmaxf(m3, __shfl_xor(m3, off));
    }

    float z0 = 0.f, z1 = 0.f, z2 = 0.f, z3 = 0.f;
    for (int p = s0 + lane; p < s1; p += 64) {
        float4 v = eesort[p];
        v.x = expf(v.x - m0); v.y = expf(v.y - m1);
        v.z = expf(v.z - m2); v.w = expf(v.w - m3);
        eesort[p] = v;
        z0 += v.x; z1 += v.y; z2 += v.z; z3 += v.w;
    }
    __threadfence_block();   // make lane-strided writebacks visible wave-wide
#pragma unroll
    for (int off = 32; off; off >>= 1) {
        z0 += __shfl_xor(z0, off);
        z1 += __shfl_xor(z1, off);
        z2 += __shfl_xor(z2, off);
        z3 += __shfl_xor(z3, off);
    }
    float i0 = z0 > 0.f ? 1.f / z0 : 0.f;
    float i1 = z1 > 0.f ? 1.f / z1 : 0.f;
    float i2 = z2 > 0.f ? 1.f / z2 : 0.f;
    float i3 = z3 > 0.f ? 1.f / z3 : 0.f;
    if (WMZ && lane == 0) {
        mbuf[n] = make_float4(m0, m1, m2, m3);
        zbuf[n] = make_float4(i0, i1, i2, i3);
    }

    float a0 = 0.f, a1 = 0.f, a2 = 0.f, a3 = 0.f;
    float c0 = 0.f, c1 = 0.f, c2 = 0.f, c3 = 0.f;
    int p = s0;
    for (; p + 1 < s1; p += 2) {
        float4 wA = eesort[p], wB = eesort[p + 1];
        int sA = srcsort[p], sB = srcsort[p + 1];
        ushort4 fA = *(const ushort4*)(featb + (size_t)sA * 256 + lane * 4);
        ushort4 fB = *(const ushort4*)(featb + (size_t)sB * 256 + lane * 4);
        a0 += wA.x * b2f(fA.x);  c0 += wB.x * b2f(fB.x);
        a1 += wA.y * b2f(fA.y);  c1 += wB.y * b2f(fB.y);
        a2 += wA.z * b2f(fA.z);  c2 += wB.z * b2f(fB.z);
        a3 += wA.w * b2f(fA.w);  c3 += wB.w * b2f(fB.w);
    }
    if (p < s1) {
        float4 wA = eesort[p];
        int sA = srcsort[p];
        ushort4 fA = *(const ushort4*)(featb + (size_t)sA * 256 + lane * 4);
        a0 += wA.x * b2f(fA.x);
        a1 += wA.y * b2f(fA.y);
        a2 += wA.z * b2f(fA.z);
        a3 += wA.w * b2f(fA.w);
    }
    a0 += c0; a1 += c1; a2 += c2; a3 += c3;

    float o0 = a0 * i0 + bias[lane];
    float o1 = a1 * i1 + bias[64 + lane];
    float o2 = a2 * i2 + bias[128 + lane];
    float o3 = a3 * i3 + bias[192 + lane];
    if (RESID) {
        ushort4 rp = *(const ushort4*)(residb + (size_t)n * 256 + lane * 4);
        o0 += b2f(rp.x); o1 += b2f(rp.y); o2 += b2f(rp.z); o3 += b2f(rp.w);
    }
    if (WF32) {
        float* op = out + (size_t)n * 256;
        op[lane] = o0;
        op[64 + lane] = o1;
        op[128 + lane] = o2;
        op[192 + lane] = o3;
    }
    if (WB16) {
        ushort4 ob;
        ob.x = f2b(o0); ob.y = f2b(o1); ob.z = f2b(o2); ob.w = f2b(o3);
        *(ushort4*)(outb + (size_t)n * 256 + lane * 4) = ob;
    }
}

// ---------------------------------------------------------------------------
// att_final: att[e] = exp(lrelu(el[src]+er[dst]) - m[dst]) * i[dst]
// ---------------------------------------------------------------------------
__global__ void att_final(const int* __restrict__ src, const int* __restrict__ dst,
                          const float* __restrict__ el, const float* __restrict__ er,
                          const float4* __restrict__ mbuf, const float4* __restrict__ zbuf,
                          float4* __restrict__ att)
{
    int e = blockIdx.x * blockDim.x + threadIdx.x;
    if (e >= EE) return;
    int s = src[e], d = dst[e];
    float4 l4 = *(const float4*)(el + (size_t)s * 4);
    float4 r4 = *(const float4*)(er + (size_t)d * 4);
    float4 m4 = mbuf[d], zi = zbuf[d];
    att[e] = make_float4(expf(lrelu(l4.x + r4.x) - m4.x) * zi.x,
                         expf(lrelu(l4.y + r4.y) - m4.y) * zi.y,
                         expf(lrelu(l4.z + r4.z) - m4.z) * zi.z,
                         expf(lrelu(l4.w + r4.w) - m4.w) * zi.w);
}

// ---------------------------------------------------------------------------
extern "C" void kernel_launch(void* const* d_in, const int* in_sizes, int n_in,
                              void* d_out, int out_size, void* d_ws, size_t ws_size,
                              hipStream_t stream)
{
    const int*   src = (const int*)d_in[0];
    const int*   dst = (const int*)d_in[1];
    const float* hc  = (const float*)d_in[2];
    const float* ht  = (const float*)d_in[3];
    const float* hr  = (const float*)d_in[4];
    const float* Wc  = (const float*)d_in[5];
    const float* Wt  = (const float*)d_in[6];
    const float* Wr  = (const float*)d_in[7];
    const float* fw  = (const float*)d_in[8];
    const float* fb  = (const float*)d_in[9];
    const float* W0  = (const float*)d_in[10];
    const float* al0 = (const float*)d_in[11];
    const float* ar0 = (const float*)d_in[12];
    const float* b0  = (const float*)d_in[13];
    const float* W1  = (const float*)d_in[14];
    const float* al1 = (const float*)d_in[15];
    const float* ar1 = (const float*)d_in[16];
    const float* b1  = (const float*)d_in[17];

    // workspace layout (bytes); round-2 proved ws_size >= 69,200,064
    char* ws = (char*)d_ws;
    unsigned short* h0b   = (unsigned short*)(ws);               // N*64  bf16 :  6,400,000
    unsigned short* h1b   = (unsigned short*)(ws + 6400000);     // N*256 bf16 : 25,600,000 (head-minor)
    unsigned short* featb = (unsigned short*)(ws + 32000000);    // N*256 bf16 : 25,600,000 (head-minor)
    float* el    = (float*)(ws + 57600000);                      //    800,000
    float* er    = (float*)(ws + 58400000);                      //    800,000
    int*   cnt   = (int*)  (ws + 59200000);                      //    200,000
    int*   offs  = (int*)  (ws + 59400000);                      //    200,064 (padded)
    int*   esort = (int*)  (ws + 59600128);                      //  3,200,000
    unsigned short* wpc = (unsigned short*)(ws + 62800128);      //  4*16KB =  65,536
    unsigned short* wpt = (unsigned short*)(ws + 62865664);      // 16*16KB = 262,144
    unsigned short* wpr = (unsigned short*)(ws + 63127808);      // 16*16KB = 262,144
    unsigned short* wp0 = (unsigned short*)(ws + 63389952);      //  2*16KB =  32,768
    unsigned short* wp1 = (unsigned short*)(ws + 63422720);      //  8*16KB = 131,072
    float4* mbuf = (float4*)(ws + 63553792);                     //    800,000
    float4* zbuf = (float4*)(ws + 64353792);                     //    800,000
    int* srcsort = (int*)  (ws + 65153792);                      //  3,200,000
    if (ws_size < 68353792ull) return;                           // end of layout

    float* outh = (float*)d_out;                       // N*256 final h
    float4* atto = (float4*)(outh + (size_t)NN * 256); // E*4 att region

    // A-pack overlays (live only during fusion)
    unsigned short* apt = (unsigned short*)d_out;                     // 51,200,000
    unsigned short* apc = (unsigned short*)((char*)d_out + 51200000); // 12,800,000
    unsigned short* apr = (unsigned short*)(ws + 6400000);            // 51,200,000

    // weight packing
    pack_w_fusion<<<(4 * 16 * 64 + 255) / 256, 256, 0, stream>>>(Wc, wpc, 129, 4);
    pack_w_fusion<<<(16 * 16 * 64 + 255) / 256, 256, 0, stream>>>(Wt, wpt, 513, 16);
    pack_w_fusion<<<(16 * 16 * 64 + 255) / 256, 256, 0, stream>>>(Wr, wpr, 513, 16);
    pack_w_gemm<0><<<(2 * 16 * 64 + 255) / 256, 256, 0, stream>>>(W0, wp0, 64, 256);
    pack_w_gemm<1><<<(8 * 16 * 64 + 255) / 256, 256, 0, stream>>>(W1, wp1, 256, 256);

    // F1: feature packs (f32 -> bf16 A-fragment order)
    pack_a<129, 4><<<NN / 16, 256, 0, stream>>>(hc, apc);
    pack_a<513, 16><<<NN / 16, 256, 0, stream>>>(ht, apt);
    pack_a<513, 16><<<NN / 16, 256, 0, stream>>>(hr, apr);

    // F2: trilinear fusion (rank-split register streaming)
    fusion_mfma<<<NN / 16, 256, 0, stream>>>(apc, apt, apr, wpc, wpt, wpr,
                                             Wc, Wt, Wr, fw, fb, h0b);

    // CSR by dst
    hipMemsetAsync(cnt, 0, NN * sizeof(int), stream);
    hist_kernel<<<(EE + 255) / 256, 256, 0, stream>>>(dst, cnt);
    scan_kernel<<<1, 1024, 0, stream>>>(cnt, offs);
    hipMemsetAsync(cnt, 0, NN * sizeof(int), stream);
    scatter_kernel<<<(EE + 255) / 256, 256, 0, stream>>>(dst, offs, cnt, esort);

    // GAT layer 0: output only bf16 h1b (head-minor); no f32 write
    gemm_reg<64><<<NN / 16, 256, 0, stream>>>(h0b, wp0, featb);
    elr_kernel<<<(NN * 64 + 255) / 256, 256, 0, stream>>>(featb, al0, ar0, el, er);
    edge_prep<<<(EE + 255) / 256, 256, 0, stream>>>(esort, src, dst, el, er, atto, srcsort);
    gat_agg<0, 0, 1, 0><<<(NN * 64 + 255) / 256, 256, 0, stream>>>(
        srcsort, offs, featb, atto, nullptr, b0, nullptr, h1b, nullptr, nullptr);

    // GAT layer 1: residual from bf16 h1b; f32 out to d_out
    gemm_reg<256><<<NN / 16, 256, 0, stream>>>(h1b, wp1, featb);
    elr_kernel<<<(NN * 64 + 255) / 256, 256, 0, stream>>>(featb, al1, ar1, el, er);
    edge_prep<<<(EE + 255) / 256, 256, 0, stream>>>(esort, src, dst, el, er, atto, srcsort);
    gat_agg<1, 1, 0, 1><<<(NN * 64 + 255) / 256, 256, 0, stream>>>(
        srcsort, offs, featb, atto, h1b, b1, outh, nullptr, mbuf, zbuf);
    att_final<<<(EE + 255) / 256, 256, 0, stream>>>(src, dst, el, er, mbuf, zbuf, atto);
}

// Round 10
// 647.872 us; speedup vs baseline: 1.4484x; 1.0201x over previous
//
#include <hip/hip_runtime.h>
#include <math.h>

#define NN 50000
#define EE 800000
#define NEG 0.2f
#define NG (NN / 16)   // 3125 node groups

using f32x4  = __attribute__((ext_vector_type(4))) float;
using bf16x8 = __attribute__((ext_vector_type(8))) short;

__device__ __forceinline__ float lrelu(float x){ return x > 0.f ? x : NEG*x; }

__device__ __forceinline__ unsigned short f2b(float f){
    unsigned int u = __float_as_uint(f);
    return (unsigned short)((u + 0x7FFFu + ((u >> 16) & 1u)) >> 16);  // RNE
}
__device__ __forceinline__ float b2f(unsigned short h){
    return __uint_as_float(((unsigned int)h) << 16);
}

// ---------------------------------------------------------------------------
// Weight packers (fragment-order bf16).
// Fusion: chunk = ct*4 + r. k < K-1 only (ones-row handled via acc init).
// ---------------------------------------------------------------------------
__global__ void pack_w_fusion(const float* __restrict__ W, unsigned short* __restrict__ out,
                              int K, int NKC)
{
    int u = blockIdx.x * blockDim.x + threadIdx.x;
    if (u >= NKC * 16 * 64) return;
    int l = u & 63, chunk = (u >> 6) & 15, kc = u >> 10;
    int ct = chunk >> 2, r = chunk & 3;
    int c = ct * 16 + (l & 15);
    int kb = kc * 32 + (l >> 4) * 8;
    bf16x8 v;
#pragma unroll
    for (int j = 0; j < 8; ++j)
        v[j] = (short)f2b(W[((size_t)r * K + kb + j) * 64 + c]);
    *(bf16x8*)(out + (size_t)u * 8) = v;
}

// GEMM weights: chunk = ct (C/16 chunks per kc); K multiple of 32.
// PERM=1: A rows are stored head-minor (k_store = d*4+h <-> k_orig = h*64+d).
template<int PERM>
__global__ void pack_w_gemm(const float* __restrict__ W, unsigned short* __restrict__ out,
                            int K, int C)
{
    int NCH = C / 16;
    int total = (K / 32) * NCH * 64;
    int u = blockIdx.x * blockDim.x + threadIdx.x;
    if (u >= total) return;
    int l = u & 63, ch = (u >> 6) % NCH, kc = u / (64 * NCH);
    int c = ch * 16 + (l & 15);
    int kb = kc * 32 + (l >> 4) * 8;
    bf16x8 v;
#pragma unroll
    for (int j = 0; j < 8; ++j) {
        int k = kb + j;
        int ko = PERM ? ((k & 3) * 64 + (k >> 2)) : k;
        v[j] = (short)f2b(W[(size_t)ko * C + c]);
    }
    *(bf16x8*)(out + (size_t)u * 8) = v;
}

// ---------------------------------------------------------------------------
// pack_a_tile: f32 features -> bf16 A-fragment order [group][kc][lane][8]
// Tile = 16 nodes x 128 k (4 kc chunks). LDS 8.3KB -> high occupancy.
//   element: node = g*16 + (l&15), k = kc*32 + (l>>4)*8 + j   (k < K-1 only)
// ---------------------------------------------------------------------------
template<int KT, int NKC>
__global__ __launch_bounds__(256) void pack_a_tile(
    const float* __restrict__ F, unsigned short* __restrict__ out)
{
    constexpr int TILES = NKC / 4;           // 4 for K=513, 1 for K=129
    __shared__ float sf[16][130];
    const int tid = threadIdx.x;
    const int g = blockIdx.x / TILES, t = blockIdx.x % TILES;
    const int nb = g * 16, k0 = t * 128;

#pragma unroll
    for (int i = 0; i < 8; ++i) {
        int idx = tid + i * 256;             // 0..2047
        int row = idx >> 7, k = idx & 127;
        sf[row][k] = F[(size_t)(nb + row) * KT + k0 + k];
    }
    __syncthreads();
    {
        int kcl = tid >> 6, l = tid & 63;
        int row = l & 15, kb = kcl * 32 + (l >> 4) * 8;
        bf16x8 o;
#pragma unroll
        for (int j = 0; j < 8; ++j) o[j] = (short)f2b(sf[row][kb + j]);
        *(bf16x8*)(out + ((size_t)(g * NKC + t * 4 + kcl) * 64 + l) * 8) = o;
    }
}

// ---------------------------------------------------------------------------
// Fusion, rank-split x 2 groups: block = 4 waves; wave w = rank w for node
// groups G0, G1. Per chunk: 2 A-loads + 4 B-loads + 8 MFMA.
// ---------------------------------------------------------------------------
template<int K, int NKC>
__device__ __forceinline__ void fusion_pass_rank2(
    const unsigned short* __restrict__ ap, const unsigned short* __restrict__ wp,
    const float* __restrict__ W, int G0, int G1c, int w, int l, f32x4 (&acc)[2][4])
{
    const int c_lo = l & 15;
#pragma unroll
    for (int ct = 0; ct < 4; ++ct) {
        float wi = W[((size_t)w * K + (K - 1)) * 64 + ct * 16 + c_lo];
        acc[0][ct] = f32x4{wi, wi, wi, wi};
        acc[1][ct] = f32x4{wi, wi, wi, wi};
    }
    const unsigned short* ab0 = ap + (size_t)G0 * NKC * 512 + l * 8;
    const unsigned short* ab1 = ap + (size_t)G1c * NKC * 512 + l * 8;
#pragma unroll
    for (int kc = 0; kc < NKC; ++kc) {
        bf16x8 af0 = *(const bf16x8*)(ab0 + kc * 512);
        bf16x8 af1 = *(const bf16x8*)(ab1 + kc * 512);
        const unsigned short* wk = wp + (size_t)kc * 8192 + w * 512 + l * 8;
#pragma unroll
        for (int ct = 0; ct < 4; ++ct) {
            bf16x8 bf = *(const bf16x8*)(wk + ct * 2048);   // chunk = ct*4 + w
            acc[0][ct] = __builtin_amdgcn_mfma_f32_16x16x32_bf16(af0, bf, acc[0][ct], 0, 0, 0);
            acc[1][ct] = __builtin_amdgcn_mfma_f32_16x16x32_bf16(af1, bf, acc[1][ct], 0, 0, 0);
        }
    }
}

__global__ __launch_bounds__(256, 2) void fusion_mfma(
    const unsigned short* __restrict__ apc, const unsigned short* __restrict__ apt,
    const unsigned short* __restrict__ apr,
    const unsigned short* __restrict__ wpc, const unsigned short* __restrict__ wpt,
    const unsigned short* __restrict__ wpr,
    const float* __restrict__ Wc, const float* __restrict__ Wt, const float* __restrict__ Wr,
    const float* __restrict__ fw, const float* __restrict__ fb,
    unsigned short* __restrict__ h0b)
{
    __shared__ float lds[4096];   // 16KB, reused sequentially per group
    const int w = threadIdx.x >> 6, l = threadIdx.x & 63;
    const int G0 = blockIdx.x * 2;
    const int G1 = G0 + 1;
    const int G1c = (G1 < NG) ? G1 : G0;

    f32x4 prod[2][4], acc[2][4];
    fusion_pass_rank2<129, 4>(apc, wpc, Wc, G0, G1c, w, l, acc);
#pragma unroll
    for (int gi = 0; gi < 2; ++gi)
#pragma unroll
        for (int ct = 0; ct < 4; ++ct) prod[gi][ct] = acc[gi][ct];
    fusion_pass_rank2<513, 16>(apt, wpt, Wt, G0, G1c, w, l, acc);
#pragma unroll
    for (int gi = 0; gi < 2; ++gi)
#pragma unroll
        for (int ct = 0; ct < 4; ++ct) prod[gi][ct] *= acc[gi][ct];
    fusion_pass_rank2<513, 16>(apr, wpr, Wr, G0, G1c, w, l, acc);
    const float fww = fw[w];
#pragma unroll
    for (int gi = 0; gi < 2; ++gi)
#pragma unroll
        for (int ct = 0; ct < 4; ++ct) prod[gi][ct] = prod[gi][ct] * acc[gi][ct] * fww;

    const int c = w * 16 + (l & 15);
    const float fbc = fb[c];
#pragma unroll
    for (int gi = 0; gi < 2; ++gi) {
        int G = G0 + gi;
        __syncthreads();
#pragma unroll
        for (int ct = 0; ct < 4; ++ct)
            *(f32x4*)&lds[((w * 4 + ct) * 64 + l) * 4] = prod[gi][ct];
        __syncthreads();
        if (G < NG) {
            f32x4 s = *(const f32x4*)&lds[((0 * 4 + w) * 64 + l) * 4];
#pragma unroll
            for (int r = 1; r < 4; ++r)
                s += *(const f32x4*)&lds[((r * 4 + w) * 64 + l) * 4];
#pragma unroll
            for (int q = 0; q < 4; ++q) {
                int n = G * 16 + (l >> 4) * 4 + q;
                float v = s[q] + fbc;
                v = v > 0.f ? v : expm1f(v);
                h0b[(size_t)n * 64 + c] = f2b(v);
            }
        }
    }
}

// ---------------------------------------------------------------------------
// feat GEMM, register-streaming x 2 groups. Output HEAD-MINOR: featb[n][d*4+h].
// ---------------------------------------------------------------------------
template<int K>
__global__ __launch_bounds__(256, 2) void gemm_reg(
    const unsigned short* __restrict__ Ab, const unsigned short* __restrict__ wp,
    unsigned short* __restrict__ featb)
{
    constexpr int NKC = K / 32;
    const int w = threadIdx.x >> 6, l = threadIdx.x & 63;
    const int G0 = blockIdx.x * 2;
    const int G1 = G0 + 1;
    const int G1c = (G1 < NG) ? G1 : G0;

    f32x4 acc[2][4];
#pragma unroll
    for (int gi = 0; gi < 2; ++gi)
#pragma unroll
        for (int i = 0; i < 4; ++i) acc[gi][i] = f32x4{0.f, 0.f, 0.f, 0.f};

    const unsigned short* ab0 = Ab + (size_t)(G0 * 16 + (l & 15)) * K + (l >> 4) * 8;
    const unsigned short* ab1 = Ab + (size_t)(G1c * 16 + (l & 15)) * K + (l >> 4) * 8;
#pragma unroll
    for (int kc = 0; kc < NKC; ++kc) {
        bf16x8 af0 = *(const bf16x8*)(ab0 + kc * 32);
        bf16x8 af1 = *(const bf16x8*)(ab1 + kc * 32);
        const unsigned short* wk = wp + ((size_t)kc * 16 + w * 4) * 512 + l * 8;
#pragma unroll
        for (int i = 0; i < 4; ++i) {
            bf16x8 bf = *(const bf16x8*)(wk + i * 512);
            acc[0][i] = __builtin_amdgcn_mfma_f32_16x16x32_bf16(af0, bf, acc[0][i], 0, 0, 0);
            acc[1][i] = __builtin_amdgcn_mfma_f32_16x16x32_bf16(af1, bf, acc[1][i], 0, 0, 0);
        }
    }
#pragma unroll
    for (int gi = 0; gi < 2; ++gi) {
        int G = G0 + gi;
        if (G >= NG) break;
#pragma unroll
        for (int i = 0; i < 4; ++i) {
            int c = (w * 4 + i) * 16 + (l & 15);
            int dm = (c & 63) * 4 + (c >> 6);   // head-minor index
#pragma unroll
            for (int q = 0; q < 4; ++q) {
                int n = G * 16 + (l >> 4) * 4 + q;
                featb[(size_t)n * 256 + dm] = f2b(acc[gi][i][q]);
            }
        }
    }
}

// ---------------------------------------------------------------------------
// el/er: one wave per node; head-minor feat -> single ushort4 load per lane.
// ---------------------------------------------------------------------------
__global__ __launch_bounds__(256) void elr_kernel(
    const unsigned short* __restrict__ featb,
    const float* __restrict__ al, const float* __restrict__ ar,
    float* __restrict__ el, float* __restrict__ er)
{
    int wid = (int)((blockIdx.x * (size_t)blockDim.x + threadIdx.x) >> 6);
    int lane = threadIdx.x & 63;
    if (wid >= NN) return;
    ushort4 f4 = *(const ushort4*)(featb + (size_t)wid * 256 + lane * 4);
    float x0 = b2f(f4.x), x1 = b2f(f4.y), x2 = b2f(f4.z), x3 = b2f(f4.w);
    float elh[4], erh[4];
    elh[0] = x0 * al[lane];        erh[0] = x0 * ar[lane];
    elh[1] = x1 * al[64 + lane];   erh[1] = x1 * ar[64 + lane];
    elh[2] = x2 * al[128 + lane];  erh[2] = x2 * ar[128 + lane];
    elh[3] = x3 * al[192 + lane];  erh[3] = x3 * ar[192 + lane];
#pragma unroll
    for (int off = 32; off; off >>= 1) {
#pragma unroll
        for (int h = 0; h < 4; ++h) {
            elh[h] += __shfl_xor(elh[h], off);
            erh[h] += __shfl_xor(erh[h], off);
        }
    }
    if (lane == 0) {
        *(float4*)(el + (size_t)wid * 4) = make_float4(elh[0], elh[1], elh[2], elh[3]);
        *(float4*)(er + (size_t)wid * 4) = make_float4(erh[0], erh[1], erh[2], erh[3]);
    }
}

// ---------------------------------------------------------------------------
// CSR build
// ---------------------------------------------------------------------------
__global__ void hist_kernel(const int* __restrict__ dst, int* __restrict__ cnt)
{
    int e = blockIdx.x * blockDim.x + threadIdx.x;
    if (e < EE) atomicAdd(&cnt[dst[e]], 1);
}

__global__ __launch_bounds__(1024) void scan_kernel(const int* __restrict__ cnt, int* __restrict__ offs)
{
    __shared__ int tmp[1024];
    const int t = threadIdx.x;
    const int C = (NN + 1023) / 1024;
    int lo = t * C, hi = min(lo + C, NN);
    int s = 0;
    for (int i = lo; i < hi; ++i) s += cnt[i];
    tmp[t] = s;
    __syncthreads();
    for (int off = 1; off < 1024; off <<= 1) {
        int v = (t >= off) ? tmp[t - off] : 0;
        __syncthreads();
        tmp[t] += v;
        __syncthreads();
    }
    int run = (t == 0) ? 0 : tmp[t - 1];
    for (int i = lo; i < hi; ++i) { offs[i] = run; run += cnt[i]; }
    if (t == 1023) offs[NN] = tmp[1023];
}

__global__ void scatter_kernel(const int* __restrict__ dst, const int* __restrict__ offs,
                               int* __restrict__ cur, int* __restrict__ esort)
{
    int e = blockIdx.x * blockDim.x + threadIdx.x;
    if (e < EE) {
        int d = dst[e];
        int p = offs[d] + atomicAdd(&cur[d], 1);
        esort[p] = e;
    }
}

// ---------------------------------------------------------------------------
// edge_prep: CSR-ordered logits + CSR-ordered src index.
// ---------------------------------------------------------------------------
__global__ void edge_prep(const int* __restrict__ esort, const int* __restrict__ src,
                          const int* __restrict__ dst,
                          const float* __restrict__ el, const float* __restrict__ er,
                          float4* __restrict__ eesort, int* __restrict__ srcsort)
{
    int p = blockIdx.x * blockDim.x + threadIdx.x;
    if (p >= EE) return;
    int e = esort[p];
    int s = src[e], d = dst[e];
    srcsort[p] = s;
    float4 l4 = *(const float4*)(el + (size_t)s * 4);
    float4 r4 = *(const float4*)(er + (size_t)d * 4);
    eesort[p] = make_float4(lrelu(l4.x + r4.x), lrelu(l4.y + r4.y),
                            lrelu(l4.z + r4.z), lrelu(l4.w + r4.w));
}

// ---------------------------------------------------------------------------
// Per-dst softmax + aggregation. One wave per node.
// Pass A: strided max. Pass B: strided exp writeback + z-sum.
// Pass C: serial edges x4-unrolled, weights ready-made, 1/z deferred.
// ---------------------------------------------------------------------------
template <int RESID, int WMZ, int WB16, int WF32>
__global__ __launch_bounds__(256) void gat_agg(
    const int* __restrict__ srcsort, const int* __restrict__ offs,
    const unsigned short* __restrict__ featb, float4* __restrict__ eesort,
    const unsigned short* __restrict__ residb, const float* __restrict__ bias,
    float* __restrict__ out, unsigned short* __restrict__ outb,
    float4* __restrict__ mbuf, float4* __restrict__ zbuf)
{
    int n = (int)((blockIdx.x * (size_t)blockDim.x + threadIdx.x) >> 6);
    int lane = threadIdx.x & 63;
    if (n >= NN) return;
    int s0 = offs[n], s1 = offs[n + 1];

    float m0 = -1e30f, m1 = -1e30f, m2 = -1e30f, m3 = -1e30f;
    for (int p = s0 + lane; p < s1; p += 64) {
        float4 v = eesort[p];
        m0 = fmaxf(m0, v.x); m1 = fmaxf(m1, v.y);
        m2 = fmaxf(m2, v.z); m3 = fmaxf(m3, v.w);
    }
#pragma unroll
    for (int off = 32; off; off >>= 1) {
        m0 = fmaxf(m0, __shfl_xor(m0, off));
        m1 = fmaxf(m1, __shfl_xor(m1, off));
        m2 = fmaxf(m2, __shfl_xor(m2, off));
        m3 = fmaxf(m3, __shfl_xor(m3, off));
    }

    float z0 = 0.f, z1 = 0.f, z2 = 0.f, z3 = 0.f;
    for (int p = s0 + lane; p < s1; p += 64) {
        float4 v = eesort[p];
        v.x = expf(v.x - m0); v.y = expf(v.y - m1);
        v.z = expf(v.z - m2); v.w = expf(v.w - m3);
        eesort[p] = v;
        z0 += v.x; z1 += v.y; z2 += v.z; z3 += v.w;
    }
    __threadfence_block();   // make lane-strided writebacks visible wave-wide
#pragma unroll
    for (int off = 32; off; off >>= 1) {
        z0 += __shfl_xor(z0, off);
        z1 += __shfl_xor(z1, off);
        z2 += __shfl_xor(z2, off);
        z3 += __shfl_xor(z3, off);
    }
    float i0 = z0 > 0.f ? 1.f / z0 : 0.f;
    float i1 = z1 > 0.f ? 1.f / z1 : 0.f;
    float i2 = z2 > 0.f ? 1.f / z2 : 0.f;
    float i3 = z3 > 0.f ? 1.f / z3 : 0.f;
    if (WMZ && lane == 0) {
        mbuf[n] = make_float4(m0, m1, m2, m3);
        zbuf[n] = make_float4(i0, i1, i2, i3);
    }

    float a0 = 0.f, a1 = 0.f, a2 = 0.f, a3 = 0.f;
    float c0 = 0.f, c1 = 0.f, c2 = 0.f, c3 = 0.f;
    int p = s0;
    for (; p + 3 < s1; p += 4) {
        float4 wA = eesort[p],     wB = eesort[p + 1];
        float4 wC = eesort[p + 2], wD = eesort[p + 3];
        int sA = srcsort[p],     sB = srcsort[p + 1];
        int sC = srcsort[p + 2], sD = srcsort[p + 3];
        ushort4 fA = *(const ushort4*)(featb + (size_t)sA * 256 + lane * 4);
        ushort4 fB = *(const ushort4*)(featb + (size_t)sB * 256 + lane * 4);
        ushort4 fC = *(const ushort4*)(featb + (size_t)sC * 256 + lane * 4);
        ushort4 fD = *(const ushort4*)(featb + (size_t)sD * 256 + lane * 4);
        a0 += wA.x * b2f(fA.x);  c0 += wB.x * b2f(fB.x);
        a1 += wA.y * b2f(fA.y);  c1 += wB.y * b2f(fB.y);
        a2 += wA.z * b2f(fA.z);  c2 += wB.z * b2f(fB.z);
        a3 += wA.w * b2f(fA.w);  c3 += wB.w * b2f(fB.w);
        a0 += wC.x * b2f(fC.x);  c0 += wD.x * b2f(fD.x);
        a1 += wC.y * b2f(fC.y);  c1 += wD.y * b2f(fD.y);
        a2 += wC.z * b2f(fC.z);  c2 += wD.z * b2f(fD.z);
        a3 += wC.w * b2f(fC.w);  c3 += wD.w * b2f(fD.w);
    }
    for (; p < s1; ++p) {
        float4 wA = eesort[p];
        int sA = srcsort[p];
        ushort4 fA = *(const ushort4*)(featb + (size_t)sA * 256 + lane * 4);
        a0 += wA.x * b2f(fA.x);
        a1 += wA.y * b2f(fA.y);
        a2 += wA.z * b2f(fA.z);
        a3 += wA.w * b2f(fA.w);
    }
    a0 += c0; a1 += c1; a2 += c2; a3 += c3;

    float o0 = a0 * i0 + bias[lane];
    float o1 = a1 * i1 + bias[64 + lane];
    float o2 = a2 * i2 + bias[128 + lane];
    float o3 = a3 * i3 + bias[192 + lane];
    if (RESID) {
        ushort4 rp = *(const ushort4*)(residb + (size_t)n * 256 + lane * 4);
        o0 += b2f(rp.x); o1 += b2f(rp.y); o2 += b2f(rp.z); o3 += b2f(rp.w);
    }
    if (WF32) {
        float* op = out + (size_t)n * 256;
        op[lane] = o0;
        op[64 + lane] = o1;
        op[128 + lane] = o2;
        op[192 + lane] = o3;
    }
    if (WB16) {
        ushort4 ob;
        ob.x = f2b(o0); ob.y = f2b(o1); ob.z = f2b(o2); ob.w = f2b(o3);
        *(ushort4*)(outb + (size_t)n * 256 + lane * 4) = ob;
    }
}

// ---------------------------------------------------------------------------
// att_final: att[e] = exp(lrelu(el[src]+er[dst]) - m[dst]) * i[dst]
// ---------------------------------------------------------------------------
__global__ void att_final(const int* __restrict__ src, const int* __restrict__ dst,
                          const float* __restrict__ el, const float* __restrict__ er,
                          const float4* __restrict__ mbuf, const float4* __restrict__ zbuf,
                          float4* __restrict__ att)
{
    int e = blockIdx.x * blockDim.x + threadIdx.x;
    if (e >= EE) return;
    int s = src[e], d = dst[e];
    float4 l4 = *(const float4*)(el + (size_t)s * 4);
    float4 r4 = *(const float4*)(er + (size_t)d * 4);
    float4 m4 = mbuf[d], zi = zbuf[d];
    att[e] = make_float4(expf(lrelu(l4.x + r4.x) - m4.x) * zi.x,
                         expf(lrelu(l4.y + r4.y) - m4.y) * zi.y,
                         expf(lrelu(l4.z + r4.z) - m4.z) * zi.z,
                         expf(lrelu(l4.w + r4.w) - m4.w) * zi.w);
}

// ---------------------------------------------------------------------------
extern "C" void kernel_launch(void* const* d_in, const int* in_sizes, int n_in,
                              void* d_out, int out_size, void* d_ws, size_t ws_size,
                              hipStream_t stream)
{
    const int*   src = (const int*)d_in[0];
    const int*   dst = (const int*)d_in[1];
    const float* hc  = (const float*)d_in[2];
    const float* ht  = (const float*)d_in[3];
    const float* hr  = (const float*)d_in[4];
    const float* Wc  = (const float*)d_in[5];
    const float* Wt  = (const float*)d_in[6];
    const float* Wr  = (const float*)d_in[7];
    const float* fw  = (const float*)d_in[8];
    const float* fb  = (const float*)d_in[9];
    const float* W0  = (const float*)d_in[10];
    const float* al0 = (const float*)d_in[11];
    const float* ar0 = (const float*)d_in[12];
    const float* b0  = (const float*)d_in[13];
    const float* W1  = (const float*)d_in[14];
    const float* al1 = (const float*)d_in[15];
    const float* ar1 = (const float*)d_in[16];
    const float* b1  = (const float*)d_in[17];

    // workspace layout (bytes); round-2 proved ws_size >= 69,200,064
    char* ws = (char*)d_ws;
    unsigned short* h0b   = (unsigned short*)(ws);               // N*64  bf16 :  6,400,000
    unsigned short* h1b   = (unsigned short*)(ws + 6400000);     // N*256 bf16 : 25,600,000 (head-minor)
    unsigned short* featb = (unsigned short*)(ws + 32000000);    // N*256 bf16 : 25,600,000 (head-minor)
    float* el    = (float*)(ws + 57600000);                      //    800,000
    float* er    = (float*)(ws + 58400000);                      //    800,000
    int*   cnt   = (int*)  (ws + 59200000);                      //    200,000
    int*   offs  = (int*)  (ws + 59400000);                      //    200,064 (padded)
    int*   esort = (int*)  (ws + 59600128);                      //  3,200,000
    unsigned short* wpc = (unsigned short*)(ws + 62800128);      //  4*16KB =  65,536
    unsigned short* wpt = (unsigned short*)(ws + 62865664);      // 16*16KB = 262,144
    unsigned short* wpr = (unsigned short*)(ws + 63127808);      // 16*16KB = 262,144
    unsigned short* wp0 = (unsigned short*)(ws + 63389952);      //  2*16KB =  32,768
    unsigned short* wp1 = (unsigned short*)(ws + 63422720);      //  8*16KB = 131,072
    float4* mbuf = (float4*)(ws + 63553792);                     //    800,000
    float4* zbuf = (float4*)(ws + 64353792);                     //    800,000
    int* srcsort = (int*)  (ws + 65153792);                      //  3,200,000
    if (ws_size < 68353792ull) return;                           // end of layout

    float* outh = (float*)d_out;                       // N*256 final h
    float4* atto = (float4*)(outh + (size_t)NN * 256); // E*4 att region

    // A-pack overlays (live only during fusion)
    unsigned short* apt = (unsigned short*)d_out;                     // 51,200,000
    unsigned short* apc = (unsigned short*)((char*)d_out + 51200000); // 12,800,000
    unsigned short* apr = (unsigned short*)(ws + 6400000);            // 51,200,000

    // weight packing
    pack_w_fusion<<<(4 * 16 * 64 + 255) / 256, 256, 0, stream>>>(Wc, wpc, 129, 4);
    pack_w_fusion<<<(16 * 16 * 64 + 255) / 256, 256, 0, stream>>>(Wt, wpt, 513, 16);
    pack_w_fusion<<<(16 * 16 * 64 + 255) / 256, 256, 0, stream>>>(Wr, wpr, 513, 16);
    pack_w_gemm<0><<<(2 * 16 * 64 + 255) / 256, 256, 0, stream>>>(W0, wp0, 64, 256);
    pack_w_gemm<1><<<(8 * 16 * 64 + 255) / 256, 256, 0, stream>>>(W1, wp1, 256, 256);

    // F1: feature packs (f32 -> bf16 A-fragment order), 128-k tiles
    pack_a_tile<129, 4><<<NG * 1, 256, 0, stream>>>(hc, apc);
    pack_a_tile<513, 16><<<NG * 4, 256, 0, stream>>>(ht, apt);
    pack_a_tile<513, 16><<<NG * 4, 256, 0, stream>>>(hr, apr);

    // F2: trilinear fusion (rank-split x 2 groups)
    fusion_mfma<<<(NG + 1) / 2, 256, 0, stream>>>(apc, apt, apr, wpc, wpt, wpr,
                                                  Wc, Wt, Wr, fw, fb, h0b);

    // CSR by dst
    hipMemsetAsync(cnt, 0, NN * sizeof(int), stream);
    hist_kernel<<<(EE + 255) / 256, 256, 0, stream>>>(dst, cnt);
    scan_kernel<<<1, 1024, 0, stream>>>(cnt, offs);
    hipMemsetAsync(cnt, 0, NN * sizeof(int), stream);
    scatter_kernel<<<(EE + 255) / 256, 256, 0, stream>>>(dst, offs, cnt, esort);

    // GAT layer 0: output only bf16 h1b (head-minor)
    gemm_reg<64><<<(NG + 1) / 2, 256, 0, stream>>>(h0b, wp0, featb);
    elr_kernel<<<(NN * 64 + 255) / 256, 256, 0, stream>>>(featb, al0, ar0, el, er);
    edge_prep<<<(EE + 255) / 256, 256, 0, stream>>>(esort, src, dst, el, er, atto, srcsort);
    gat_agg<0, 0, 1, 0><<<(NN * 64 + 255) / 256, 256, 0, stream>>>(
        srcsort, offs, featb, atto, nullptr, b0, nullptr, h1b, nullptr, nullptr);

    // GAT layer 1: residual from bf16 h1b; f32 out to d_out
    gemm_reg<256><<<(NG + 1) / 2, 256, 0, stream>>>(h1b, wp1, featb);
    elr_kernel<<<(NN * 64 + 255) / 256, 256, 0, stream>>>(featb, al1, ar1, el, er);
    edge_prep<<<(EE + 255) / 256, 256, 0, stream>>>(esort, src, dst, el, er, atto, srcsort);
    gat_agg<1, 1, 0, 1><<<(NN * 64 + 255) / 256, 256, 0, stream>>>(
        srcsort, offs, featb, atto, h1b, b1, outh, nullptr, mbuf, zbuf);
    att_final<<<(EE + 255) / 256, 256, 0, stream>>>(src, dst, el, er, mbuf, zbuf, atto);
}

// Round 11
// 631.403 us; speedup vs baseline: 1.4862x; 1.0261x over previous
//
#include <hip/hip_runtime.h>
#include <math.h>

#define NN 50000
#define EE 800000
#define NEG 0.2f
#define NG (NN / 16)   // 3125 node groups

using f32x4  = __attribute__((ext_vector_type(4))) float;
using bf16x8 = __attribute__((ext_vector_type(8))) short;

__device__ __forceinline__ float lrelu(float x){ return x > 0.f ? x : NEG*x; }

__device__ __forceinline__ unsigned short f2b(float f){
    unsigned int u = __float_as_uint(f);
    return (unsigned short)((u + 0x7FFFu + ((u >> 16) & 1u)) >> 16);  // RNE
}
__device__ __forceinline__ float b2f(unsigned short h){
    return __uint_as_float(((unsigned int)h) << 16);
}

// ---------------------------------------------------------------------------
// Weight packers (fragment-order bf16).
// Fusion: chunk = ct*4 + r. k < K-1 only (ones-row handled via acc init).
// ---------------------------------------------------------------------------
__global__ void pack_w_fusion(const float* __restrict__ W, unsigned short* __restrict__ out,
                              int K, int NKC)
{
    int u = blockIdx.x * blockDim.x + threadIdx.x;
    if (u >= NKC * 16 * 64) return;
    int l = u & 63, chunk = (u >> 6) & 15, kc = u >> 10;
    int ct = chunk >> 2, r = chunk & 3;
    int c = ct * 16 + (l & 15);
    int kb = kc * 32 + (l >> 4) * 8;
    bf16x8 v;
#pragma unroll
    for (int j = 0; j < 8; ++j)
        v[j] = (short)f2b(W[((size_t)r * K + kb + j) * 64 + c]);
    *(bf16x8*)(out + (size_t)u * 8) = v;
}

// GEMM weights: chunk = ct (C/16 chunks per kc); K multiple of 32.
// PERM=1: A rows are stored head-minor (k_store = d*4+h <-> k_orig = h*64+d).
template<int PERM>
__global__ void pack_w_gemm(const float* __restrict__ W, unsigned short* __restrict__ out,
                            int K, int C)
{
    int NCH = C / 16;
    int total = (K / 32) * NCH * 64;
    int u = blockIdx.x * blockDim.x + threadIdx.x;
    if (u >= total) return;
    int l = u & 63, ch = (u >> 6) % NCH, kc = u / (64 * NCH);
    int c = ch * 16 + (l & 15);
    int kb = kc * 32 + (l >> 4) * 8;
    bf16x8 v;
#pragma unroll
    for (int j = 0; j < 8; ++j) {
        int k = kb + j;
        int ko = PERM ? ((k & 3) * 64 + (k >> 2)) : k;
        v[j] = (short)f2b(W[(size_t)ko * C + c]);
    }
    *(bf16x8*)(out + (size_t)u * 8) = v;
}

// ---------------------------------------------------------------------------
// pack_a_tile: f32 features -> bf16 A-fragment order [group][kc][lane][8]
// Tile = 16 nodes x 128 k (4 kc chunks). LDS 8.3KB -> high occupancy.
// ---------------------------------------------------------------------------
template<int KT, int NKC>
__global__ __launch_bounds__(256) void pack_a_tile(
    const float* __restrict__ F, unsigned short* __restrict__ out)
{
    constexpr int TILES = NKC / 4;           // 4 for K=513, 1 for K=129
    __shared__ float sf[16][130];
    const int tid = threadIdx.x;
    const int g = blockIdx.x / TILES, t = blockIdx.x % TILES;
    const int nb = g * 16, k0 = t * 128;

#pragma unroll
    for (int i = 0; i < 8; ++i) {
        int idx = tid + i * 256;             // 0..2047
        int row = idx >> 7, k = idx & 127;
        sf[row][k] = F[(size_t)(nb + row) * KT + k0 + k];
    }
    __syncthreads();
    {
        int kcl = tid >> 6, l = tid & 63;
        int row = l & 15, kb = kcl * 32 + (l >> 4) * 8;
        bf16x8 o;
#pragma unroll
        for (int j = 0; j < 8; ++j) o[j] = (short)f2b(sf[row][kb + j]);
        *(bf16x8*)(out + ((size_t)(g * NKC + t * 4 + kcl) * 64 + l) * 8) = o;
    }
}

// ---------------------------------------------------------------------------
// Fusion: block = 4 waves on ONE 16-node group (3125 blocks); wave w = rank w.
// Pass 1 (hc, NKC=4) fills prod. Pass 2 interleaves ht & hr in one loop:
// per kc, 2 independent A-streams + 8 B-loads + 8 MFMA -> 2x per-wave MLP
// at unchanged block count (round-10 A/B showed block count dominates).
// ---------------------------------------------------------------------------
__global__ __launch_bounds__(256) void fusion_mfma(
    const unsigned short* __restrict__ apc, const unsigned short* __restrict__ apt,
    const unsigned short* __restrict__ apr,
    const unsigned short* __restrict__ wpc, const unsigned short* __restrict__ wpt,
    const unsigned short* __restrict__ wpr,
    const float* __restrict__ Wc, const float* __restrict__ Wt, const float* __restrict__ Wr,
    const float* __restrict__ fw, const float* __restrict__ fb,
    unsigned short* __restrict__ h0b)
{
    __shared__ float lds[4096];   // 16KB rank-exchange
    const int w = threadIdx.x >> 6, l = threadIdx.x & 63;
    const int G = blockIdx.x;
    const int c_lo = l & 15;

    f32x4 prod[4], acct[4], accr[4];

    // pass 1: hc (K=129, 4 chunks)
#pragma unroll
    for (int ct = 0; ct < 4; ++ct) {
        float wi = Wc[((size_t)w * 129 + 128) * 64 + ct * 16 + c_lo];
        prod[ct] = f32x4{wi, wi, wi, wi};
    }
    {
        const unsigned short* ab = apc + (size_t)G * 4 * 512 + l * 8;
#pragma unroll
        for (int kc = 0; kc < 4; ++kc) {
            bf16x8 af = *(const bf16x8*)(ab + kc * 512);
            const unsigned short* wk = wpc + (size_t)kc * 8192 + w * 512 + l * 8;
#pragma unroll
            for (int ct = 0; ct < 4; ++ct) {
                bf16x8 bf = *(const bf16x8*)(wk + ct * 2048);
                prod[ct] = __builtin_amdgcn_mfma_f32_16x16x32_bf16(af, bf, prod[ct], 0, 0, 0);
            }
        }
    }

    // pass 2: ht & hr interleaved (K=513, 16 chunks each)
#pragma unroll
    for (int ct = 0; ct < 4; ++ct) {
        float wt = Wt[((size_t)w * 513 + 512) * 64 + ct * 16 + c_lo];
        float wr = Wr[((size_t)w * 513 + 512) * 64 + ct * 16 + c_lo];
        acct[ct] = f32x4{wt, wt, wt, wt};
        accr[ct] = f32x4{wr, wr, wr, wr};
    }
    {
        const unsigned short* abt = apt + (size_t)G * 16 * 512 + l * 8;
        const unsigned short* abr = apr + (size_t)G * 16 * 512 + l * 8;
#pragma unroll
        for (int kc = 0; kc < 16; ++kc) {
            bf16x8 aft = *(const bf16x8*)(abt + kc * 512);
            bf16x8 afr = *(const bf16x8*)(abr + kc * 512);
            const unsigned short* wkt = wpt + (size_t)kc * 8192 + w * 512 + l * 8;
            const unsigned short* wkr = wpr + (size_t)kc * 8192 + w * 512 + l * 8;
#pragma unroll
            for (int ct = 0; ct < 4; ++ct) {
                bf16x8 bft = *(const bf16x8*)(wkt + ct * 2048);
                bf16x8 bfr = *(const bf16x8*)(wkr + ct * 2048);
                acct[ct] = __builtin_amdgcn_mfma_f32_16x16x32_bf16(aft, bft, acct[ct], 0, 0, 0);
                accr[ct] = __builtin_amdgcn_mfma_f32_16x16x32_bf16(afr, bfr, accr[ct], 0, 0, 0);
            }
        }
    }

    const float fww = fw[w];
#pragma unroll
    for (int ct = 0; ct < 4; ++ct) {
        prod[ct] = prod[ct] * acct[ct] * accr[ct] * fww;
        *(f32x4*)&lds[((w * 4 + ct) * 64 + l) * 4] = prod[ct];
    }
    __syncthreads();

    // wave w sums the 4 ranks for col-tile ct = w
    f32x4 s = *(const f32x4*)&lds[((0 * 4 + w) * 64 + l) * 4];
#pragma unroll
    for (int r = 1; r < 4; ++r)
        s += *(const f32x4*)&lds[((r * 4 + w) * 64 + l) * 4];

    const int c = w * 16 + c_lo;
    const float fbc = fb[c];
#pragma unroll
    for (int q = 0; q < 4; ++q) {
        int n = G * 16 + (l >> 4) * 4 + q;
        float v = s[q] + fbc;
        v = v > 0.f ? v : expm1f(v);
        h0b[(size_t)n * 64 + c] = f2b(v);
    }
}

// ---------------------------------------------------------------------------
// feat GEMM, register-streaming, ONE group per block (3125 blocks — the
// round-10 A/B showed block count beats per-wave ILP here).
// Output HEAD-MINOR: featb[n][d*4+h].
// ---------------------------------------------------------------------------
template<int K>
__global__ __launch_bounds__(256) void gemm_reg(
    const unsigned short* __restrict__ Ab, const unsigned short* __restrict__ wp,
    unsigned short* __restrict__ featb)
{
    constexpr int NKC = K / 32;
    const int w = threadIdx.x >> 6, l = threadIdx.x & 63;
    const int nb = blockIdx.x * 16;

    f32x4 acc[4];
#pragma unroll
    for (int i = 0; i < 4; ++i) acc[i] = f32x4{0.f, 0.f, 0.f, 0.f};

    const unsigned short* abase = Ab + (size_t)(nb + (l & 15)) * K + (l >> 4) * 8;
#pragma unroll
    for (int kc = 0; kc < NKC; ++kc) {
        bf16x8 af = *(const bf16x8*)(abase + kc * 32);
        const unsigned short* wk = wp + ((size_t)kc * 16 + w * 4) * 512 + l * 8;
#pragma unroll
        for (int i = 0; i < 4; ++i) {
            bf16x8 bf = *(const bf16x8*)(wk + i * 512);
            acc[i] = __builtin_amdgcn_mfma_f32_16x16x32_bf16(af, bf, acc[i], 0, 0, 0);
        }
    }
#pragma unroll
    for (int i = 0; i < 4; ++i) {
        int c = (w * 4 + i) * 16 + (l & 15);
        int dm = (c & 63) * 4 + (c >> 6);   // head-minor index
#pragma unroll
        for (int q = 0; q < 4; ++q) {
            int n = nb + (l >> 4) * 4 + q;
            featb[(size_t)n * 256 + dm] = f2b(acc[i][q]);
        }
    }
}

// ---------------------------------------------------------------------------
// el/er: one wave per node; head-minor feat -> single ushort4 load per lane.
// ---------------------------------------------------------------------------
__global__ __launch_bounds__(256) void elr_kernel(
    const unsigned short* __restrict__ featb,
    const float* __restrict__ al, const float* __restrict__ ar,
    float* __restrict__ el, float* __restrict__ er)
{
    int wid = (int)((blockIdx.x * (size_t)blockDim.x + threadIdx.x) >> 6);
    int lane = threadIdx.x & 63;
    if (wid >= NN) return;
    ushort4 f4 = *(const ushort4*)(featb + (size_t)wid * 256 + lane * 4);
    float x0 = b2f(f4.x), x1 = b2f(f4.y), x2 = b2f(f4.z), x3 = b2f(f4.w);
    float elh[4], erh[4];
    elh[0] = x0 * al[lane];        erh[0] = x0 * ar[lane];
    elh[1] = x1 * al[64 + lane];   erh[1] = x1 * ar[64 + lane];
    elh[2] = x2 * al[128 + lane];  erh[2] = x2 * ar[128 + lane];
    elh[3] = x3 * al[192 + lane];  erh[3] = x3 * ar[192 + lane];
#pragma unroll
    for (int off = 32; off; off >>= 1) {
#pragma unroll
        for (int h = 0; h < 4; ++h) {
            elh[h] += __shfl_xor(elh[h], off);
            erh[h] += __shfl_xor(erh[h], off);
        }
    }
    if (lane == 0) {
        *(float4*)(el + (size_t)wid * 4) = make_float4(elh[0], elh[1], elh[2], elh[3]);
        *(float4*)(er + (size_t)wid * 4) = make_float4(erh[0], erh[1], erh[2], erh[3]);
    }
}

// ---------------------------------------------------------------------------
// CSR build
// ---------------------------------------------------------------------------
__global__ void hist_kernel(const int* __restrict__ dst, int* __restrict__ cnt)
{
    int e = blockIdx.x * blockDim.x + threadIdx.x;
    if (e < EE) atomicAdd(&cnt[dst[e]], 1);
}

__global__ __launch_bounds__(1024) void scan_kernel(const int* __restrict__ cnt, int* __restrict__ offs)
{
    __shared__ int tmp[1024];
    const int t = threadIdx.x;
    const int C = (NN + 1023) / 1024;
    int lo = t * C, hi = min(lo + C, NN);
    int s = 0;
    for (int i = lo; i < hi; ++i) s += cnt[i];
    tmp[t] = s;
    __syncthreads();
    for (int off = 1; off < 1024; off <<= 1) {
        int v = (t >= off) ? tmp[t - off] : 0;
        __syncthreads();
        tmp[t] += v;
        __syncthreads();
    }
    int run = (t == 0) ? 0 : tmp[t - 1];
    for (int i = lo; i < hi; ++i) { offs[i] = run; run += cnt[i]; }
    if (t == 1023) offs[NN] = tmp[1023];
}

__global__ void scatter_kernel(const int* __restrict__ dst, const int* __restrict__ offs,
                               int* __restrict__ cur, int* __restrict__ esort)
{
    int e = blockIdx.x * blockDim.x + threadIdx.x;
    if (e < EE) {
        int d = dst[e];
        int p = offs[d] + atomicAdd(&cur[d], 1);
        esort[p] = e;
    }
}

// ---------------------------------------------------------------------------
// edge_prep: CSR-ordered logits + CSR-ordered src index.
// ---------------------------------------------------------------------------
__global__ void edge_prep(const int* __restrict__ esort, const int* __restrict__ src,
                          const int* __restrict__ dst,
                          const float* __restrict__ el, const float* __restrict__ er,
                          float4* __restrict__ eesort, int* __restrict__ srcsort)
{
    int p = blockIdx.x * blockDim.x + threadIdx.x;
    if (p >= EE) return;
    int e = esort[p];
    int s = src[e], d = dst[e];
    srcsort[p] = s;
    float4 l4 = *(const float4*)(el + (size_t)s * 4);
    float4 r4 = *(const float4*)(er + (size_t)d * 4);
    eesort[p] = make_float4(lrelu(l4.x + r4.x), lrelu(l4.y + r4.y),
                            lrelu(l4.z + r4.z), lrelu(l4.w + r4.w));
}

// ---------------------------------------------------------------------------
// Per-dst softmax + aggregation. One wave per node.
// Pass A: strided max. Pass B: strided exp writeback + z-sum.
// Pass C: serial edges x4-unrolled, weights ready-made, 1/z deferred.
// ---------------------------------------------------------------------------
template <int RESID, int WMZ, int WB16, int WF32>
__global__ __launch_bounds__(256) void gat_agg(
    const int* __restrict__ srcsort, const int* __restrict__ offs,
    const unsigned short* __restrict__ featb, float4* __restrict__ eesort,
    const unsigned short* __restrict__ residb, const float* __restrict__ bias,
    float* __restrict__ out, unsigned short* __restrict__ outb,
    float4* __restrict__ mbuf, float4* __restrict__ zbuf)
{
    int n = (int)((blockIdx.x * (size_t)blockDim.x + threadIdx.x) >> 6);
    int lane = threadIdx.x & 63;
    if (n >= NN) return;
    int s0 = offs[n], s1 = offs[n + 1];

    float m0 = -1e30f, m1 = -1e30f, m2 = -1e30f, m3 = -1e30f;
    for (int p = s0 + lane; p < s1; p += 64) {
        float4 v = eesort[p];
        m0 = fmaxf(m0, v.x); m1 = fmaxf(m1, v.y);
        m2 = fmaxf(m2, v.z); m3 = fmaxf(m3, v.w);
    }
#pragma unroll
    for (int off = 32; off; off >>= 1) {
        m0 = fmaxf(m0, __shfl_xor(m0, off));
        m1 = fmaxf(m1, __shfl_xor(m1, off));
        m2 = fmaxf(m2, __shfl_xor(m2, off));
        m3 = fmaxf(m3, __shfl_xor(m3, off));
    }

    float z0 = 0.f, z1 = 0.f, z2 = 0.f, z3 = 0.f;
    for (int p = s0 + lane; p < s1; p += 64) {
        float4 v = eesort[p];
        v.x = expf(v.x - m0); v.y = expf(v.y - m1);
        v.z = expf(v.z - m2); v.w = expf(v.w - m3);
        eesort[p] = v;
        z0 += v.x; z1 += v.y; z2 += v.z; z3 += v.w;
    }
    __threadfence_block();   // make lane-strided writebacks visible wave-wide
#pragma unroll
    for (int off = 32; off; off >>= 1) {
        z0 += __shfl_xor(z0, off);
        z1 += __shfl_xor(z1, off);
        z2 += __shfl_xor(z2, off);
        z3 += __shfl_xor(z3, off);
    }
    float i0 = z0 > 0.f ? 1.f / z0 : 0.f;
    float i1 = z1 > 0.f ? 1.f / z1 : 0.f;
    float i2 = z2 > 0.f ? 1.f / z2 : 0.f;
    float i3 = z3 > 0.f ? 1.f / z3 : 0.f;
    if (WMZ && lane == 0) {
        mbuf[n] = make_float4(m0, m1, m2, m3);
        zbuf[n] = make_float4(i0, i1, i2, i3);
    }

    float a0 = 0.f, a1 = 0.f, a2 = 0.f, a3 = 0.f;
    float c0 = 0.f, c1 = 0.f, c2 = 0.f, c3 = 0.f;
    int p = s0;
    for (; p + 3 < s1; p += 4) {
        float4 wA = eesort[p],     wB = eesort[p + 1];
        float4 wC = eesort[p + 2], wD = eesort[p + 3];
        int sA = srcsort[p],     sB = srcsort[p + 1];
        int sC = srcsort[p + 2], sD = srcsort[p + 3];
        ushort4 fA = *(const ushort4*)(featb + (size_t)sA * 256 + lane * 4);
        ushort4 fB = *(const ushort4*)(featb + (size_t)sB * 256 + lane * 4);
        ushort4 fC = *(const ushort4*)(featb + (size_t)sC * 256 + lane * 4);
        ushort4 fD = *(const ushort4*)(featb + (size_t)sD * 256 + lane * 4);
        a0 += wA.x * b2f(fA.x);  c0 += wB.x * b2f(fB.x);
        a1 += wA.y * b2f(fA.y);  c1 += wB.y * b2f(fB.y);
        a2 += wA.z * b2f(fA.z);  c2 += wB.z * b2f(fB.z);
        a3 += wA.w * b2f(fA.w);  c3 += wB.w * b2f(fB.w);
        a0 += wC.x * b2f(fC.x);  c0 += wD.x * b2f(fD.x);
        a1 += wC.y * b2f(fC.y);  c1 += wD.y * b2f(fD.y);
        a2 += wC.z * b2f(fC.z);  c2 += wD.z * b2f(fD.z);
        a3 += wC.w * b2f(fC.w);  c3 += wD.w * b2f(fD.w);
    }
    for (; p < s1; ++p) {
        float4 wA = eesort[p];
        int sA = srcsort[p];
        ushort4 fA = *(const ushort4*)(featb + (size_t)sA * 256 + lane * 4);
        a0 += wA.x * b2f(fA.x);
        a1 += wA.y * b2f(fA.y);
        a2 += wA.z * b2f(fA.z);
        a3 += wA.w * b2f(fA.w);
    }
    a0 += c0; a1 += c1; a2 += c2; a3 += c3;

    float o0 = a0 * i0 + bias[lane];
    float o1 = a1 * i1 + bias[64 + lane];
    float o2 = a2 * i2 + bias[128 + lane];
    float o3 = a3 * i3 + bias[192 + lane];
    if (RESID) {
        ushort4 rp = *(const ushort4*)(residb + (size_t)n * 256 + lane * 4);
        o0 += b2f(rp.x); o1 += b2f(rp.y); o2 += b2f(rp.z); o3 += b2f(rp.w);
    }
    if (WF32) {
        float* op = out + (size_t)n * 256;
        op[lane] = o0;
        op[64 + lane] = o1;
        op[128 + lane] = o2;
        op[192 + lane] = o3;
    }
    if (WB16) {
        ushort4 ob;
        ob.x = f2b(o0); ob.y = f2b(o1); ob.z = f2b(o2); ob.w = f2b(o3);
        *(ushort4*)(outb + (size_t)n * 256 + lane * 4) = ob;
    }
}

// ---------------------------------------------------------------------------
// att_final: att[e] = exp(lrelu(el[src]+er[dst]) - m[dst]) * i[dst]
// ---------------------------------------------------------------------------
__global__ void att_final(const int* __restrict__ src, const int* __restrict__ dst,
                          const float* __restrict__ el, const float* __restrict__ er,
                          const float4* __restrict__ mbuf, const float4* __restrict__ zbuf,
                          float4* __restrict__ att)
{
    int e = blockIdx.x * blockDim.x + threadIdx.x;
    if (e >= EE) return;
    int s = src[e], d = dst[e];
    float4 l4 = *(const float4*)(el + (size_t)s * 4);
    float4 r4 = *(const float4*)(er + (size_t)d * 4);
    float4 m4 = mbuf[d], zi = zbuf[d];
    att[e] = make_float4(expf(lrelu(l4.x + r4.x) - m4.x) * zi.x,
                         expf(lrelu(l4.y + r4.y) - m4.y) * zi.y,
                         expf(lrelu(l4.z + r4.z) - m4.z) * zi.z,
                         expf(lrelu(l4.w + r4.w) - m4.w) * zi.w);
}

// ---------------------------------------------------------------------------
extern "C" void kernel_launch(void* const* d_in, const int* in_sizes, int n_in,
                              void* d_out, int out_size, void* d_ws, size_t ws_size,
                              hipStream_t stream)
{
    const int*   src = (const int*)d_in[0];
    const int*   dst = (const int*)d_in[1];
    const float* hc  = (const float*)d_in[2];
    const float* ht  = (const float*)d_in[3];
    const float* hr  = (const float*)d_in[4];
    const float* Wc  = (const float*)d_in[5];
    const float* Wt  = (const float*)d_in[6];
    const float* Wr  = (const float*)d_in[7];
    const float* fw  = (const float*)d_in[8];
    const float* fb  = (const float*)d_in[9];
    const float* W0  = (const float*)d_in[10];
    const float* al0 = (const float*)d_in[11];
    const float* ar0 = (const float*)d_in[12];
    const float* b0  = (const float*)d_in[13];
    const float* W1  = (const float*)d_in[14];
    const float* al1 = (const float*)d_in[15];
    const float* ar1 = (const float*)d_in[16];
    const float* b1  = (const float*)d_in[17];

    // workspace layout (bytes); round-2 proved ws_size >= 69,200,064
    char* ws = (char*)d_ws;
    unsigned short* h0b   = (unsigned short*)(ws);               // N*64  bf16 :  6,400,000
    unsigned short* h1b   = (unsigned short*)(ws + 6400000);     // N*256 bf16 : 25,600,000 (head-minor)
    unsigned short* featb = (unsigned short*)(ws + 32000000);    // N*256 bf16 : 25,600,000 (head-minor)
    float* el    = (float*)(ws + 57600000);                      //    800,000
    float* er    = (float*)(ws + 58400000);                      //    800,000
    int*   cnt   = (int*)  (ws + 59200000);                      //    200,000
    int*   offs  = (int*)  (ws + 59400000);                      //    200,064 (padded)
    int*   esort = (int*)  (ws + 59600128);                      //  3,200,000
    unsigned short* wpc = (unsigned short*)(ws + 62800128);      //  4*16KB =  65,536
    unsigned short* wpt = (unsigned short*)(ws + 62865664);      // 16*16KB = 262,144
    unsigned short* wpr = (unsigned short*)(ws + 63127808);      // 16*16KB = 262,144
    unsigned short* wp0 = (unsigned short*)(ws + 63389952);      //  2*16KB =  32,768
    unsigned short* wp1 = (unsigned short*)(ws + 63422720);      //  8*16KB = 131,072
    float4* mbuf = (float4*)(ws + 63553792);                     //    800,000
    float4* zbuf = (float4*)(ws + 64353792);                     //    800,000
    int* srcsort = (int*)  (ws + 65153792);                      //  3,200,000
    if (ws_size < 68353792ull) return;                           // end of layout

    float* outh = (float*)d_out;                       // N*256 final h
    float4* atto = (float4*)(outh + (size_t)NN * 256); // E*4 att region

    // A-pack overlays (live only during fusion)
    unsigned short* apt = (unsigned short*)d_out;                     // 51,200,000
    unsigned short* apc = (unsigned short*)((char*)d_out + 51200000); // 12,800,000
    unsigned short* apr = (unsigned short*)(ws + 6400000);            // 51,200,000

    // weight packing
    pack_w_fusion<<<(4 * 16 * 64 + 255) / 256, 256, 0, stream>>>(Wc, wpc, 129, 4);
    pack_w_fusion<<<(16 * 16 * 64 + 255) / 256, 256, 0, stream>>>(Wt, wpt, 513, 16);
    pack_w_fusion<<<(16 * 16 * 64 + 255) / 256, 256, 0, stream>>>(Wr, wpr, 513, 16);
    pack_w_gemm<0><<<(2 * 16 * 64 + 255) / 256, 256, 0, stream>>>(W0, wp0, 64, 256);
    pack_w_gemm<1><<<(8 * 16 * 64 + 255) / 256, 256, 0, stream>>>(W1, wp1, 256, 256);

    // F1: feature packs (f32 -> bf16 A-fragment order), 128-k tiles
    pack_a_tile<129, 4><<<NG * 1, 256, 0, stream>>>(hc, apc);
    pack_a_tile<513, 16><<<NG * 4, 256, 0, stream>>>(ht, apt);
    pack_a_tile<513, 16><<<NG * 4, 256, 0, stream>>>(hr, apr);

    // F2: trilinear fusion (rank-split, dual-interleaved ht/hr pass)
    fusion_mfma<<<NG, 256, 0, stream>>>(apc, apt, apr, wpc, wpt, wpr,
                                        Wc, Wt, Wr, fw, fb, h0b);

    // CSR by dst
    hipMemsetAsync(cnt, 0, NN * sizeof(int), stream);
    hist_kernel<<<(EE + 255) / 256, 256, 0, stream>>>(dst, cnt);
    scan_kernel<<<1, 1024, 0, stream>>>(cnt, offs);
    hipMemsetAsync(cnt, 0, NN * sizeof(int), stream);
    scatter_kernel<<<(EE + 255) / 256, 256, 0, stream>>>(dst, offs, cnt, esort);

    // GAT layer 0: output only bf16 h1b (head-minor)
    gemm_reg<64><<<NG, 256, 0, stream>>>(h0b, wp0, featb);
    elr_kernel<<<(NN * 64 + 255) / 256, 256, 0, stream>>>(featb, al0, ar0, el, er);
    edge_prep<<<(EE + 255) / 256, 256, 0, stream>>>(esort, src, dst, el, er, atto, srcsort);
    gat_agg<0, 0, 1, 0><<<(NN * 64 + 255) / 256, 256, 0, stream>>>(
        srcsort, offs, featb, atto, nullptr, b0, nullptr, h1b, nullptr, nullptr);

    // GAT layer 1: residual from bf16 h1b; f32 out to d_out
    gemm_reg<256><<<NG, 256, 0, stream>>>(h1b, wp1, featb);
    elr_kernel<<<(NN * 64 + 255) / 256, 256, 0, stream>>>(featb, al1, ar1, el, er);
    edge_prep<<<(EE + 255) / 256, 256, 0, stream>>>(esort, src, dst, el, er, atto, srcsort);
    gat_agg<1, 1, 0, 1><<<(NN * 64 + 255) / 256, 256, 0, stream>>>(
        srcsort, offs, featb, atto, h1b, b1, outh, nullptr, mbuf, zbuf);
    att_final<<<(EE + 255) / 256, 256, 0, stream>>>(src, dst, el, er, mbuf, zbuf, atto);
}

// Round 12
// 628.788 us; speedup vs baseline: 1.4924x; 1.0042x over previous
//
#include <hip/hip_runtime.h>
#include <math.h>

#define NN 50000
#define EE 800000
#define NEG 0.2f
#define NG (NN / 16)   // 3125 node groups

using f32x4  = __attribute__((ext_vector_type(4))) float;
using bf16x8 = __attribute__((ext_vector_type(8))) short;

__device__ __forceinline__ float lrelu(float x){ return x > 0.f ? x : NEG*x; }

__device__ __forceinline__ unsigned short f2b(float f){
    unsigned int u = __float_as_uint(f);
    return (unsigned short)((u + 0x7FFFu + ((u >> 16) & 1u)) >> 16);  // RNE
}
__device__ __forceinline__ float b2f(unsigned short h){
    return __uint_as_float(((unsigned int)h) << 16);
}

// ---------------------------------------------------------------------------
// Weight packers (fragment-order bf16).
// Fusion: chunk = ct*4 + r. k < K-1 only (ones-row handled via acc init).
// ---------------------------------------------------------------------------
__global__ void pack_w_fusion(const float* __restrict__ W, unsigned short* __restrict__ out,
                              int K, int NKC)
{
    int u = blockIdx.x * blockDim.x + threadIdx.x;
    if (u >= NKC * 16 * 64) return;
    int l = u & 63, chunk = (u >> 6) & 15, kc = u >> 10;
    int ct = chunk >> 2, r = chunk & 3;
    int c = ct * 16 + (l & 15);
    int kb = kc * 32 + (l >> 4) * 8;
    bf16x8 v;
#pragma unroll
    for (int j = 0; j < 8; ++j)
        v[j] = (short)f2b(W[((size_t)r * K + kb + j) * 64 + c]);
    *(bf16x8*)(out + (size_t)u * 8) = v;
}

// GEMM weights: chunk = ct (C/16 chunks per kc); K multiple of 32.
// PERM=1: A rows are stored head-minor (k_store = d*4+h <-> k_orig = h*64+d).
template<int PERM>
__global__ void pack_w_gemm(const float* __restrict__ W, unsigned short* __restrict__ out,
                            int K, int C)
{
    int NCH = C / 16;
    int total = (K / 32) * NCH * 64;
    int u = blockIdx.x * blockDim.x + threadIdx.x;
    if (u >= total) return;
    int l = u & 63, ch = (u >> 6) % NCH, kc = u / (64 * NCH);
    int c = ch * 16 + (l & 15);
    int kb = kc * 32 + (l >> 4) * 8;
    bf16x8 v;
#pragma unroll
    for (int j = 0; j < 8; ++j) {
        int k = kb + j;
        int ko = PERM ? ((k & 3) * 64 + (k >> 2)) : k;
        v[j] = (short)f2b(W[(size_t)ko * C + c]);
    }
    *(bf16x8*)(out + (size_t)u * 8) = v;
}

// ---------------------------------------------------------------------------
// pack_a_tile: f32 features -> bf16 A-fragment order [group][kc][lane][8]
// Tile = 16 nodes x 128 k (4 kc chunks). LDS 8.3KB -> high occupancy.
// ---------------------------------------------------------------------------
template<int KT, int NKC>
__global__ __launch_bounds__(256) void pack_a_tile(
    const float* __restrict__ F, unsigned short* __restrict__ out)
{
    constexpr int TILES = NKC / 4;           // 4 for K=513, 1 for K=129
    __shared__ float sf[16][130];
    const int tid = threadIdx.x;
    const int g = blockIdx.x / TILES, t = blockIdx.x % TILES;
    const int nb = g * 16, k0 = t * 128;

#pragma unroll
    for (int i = 0; i < 8; ++i) {
        int idx = tid + i * 256;             // 0..2047
        int row = idx >> 7, k = idx & 127;
        sf[row][k] = F[(size_t)(nb + row) * KT + k0 + k];
    }
    __syncthreads();
    {
        int kcl = tid >> 6, l = tid & 63;
        int row = l & 15, kb = kcl * 32 + (l >> 4) * 8;
        bf16x8 o;
#pragma unroll
        for (int j = 0; j < 8; ++j) o[j] = (short)f2b(sf[row][kb + j]);
        *(bf16x8*)(out + ((size_t)(g * NKC + t * 4 + kcl) * 64 + l) * 8) = o;
    }
}

// ---------------------------------------------------------------------------
// Fusion pass with MANUAL register prefetch: A-frags for a half-pass (up to
// 8 chunks = 32 VGPR) loaded into a register array BEFORE the MFMA loop;
// B double-buffered 1 chunk ahead. Forces deep memory-level parallelism the
// compiler refuses to create on its own (VGPR stuck at 64-68, R9-R11).
// ---------------------------------------------------------------------------
template<int K, int NKC>
__device__ __forceinline__ void fusion_pass_rank(
    const unsigned short* __restrict__ ap, const unsigned short* __restrict__ wp,
    const float* __restrict__ W, int G, int w, int l, f32x4 (&acc)[4])
{
    const int c_lo = l & 15;
#pragma unroll
    for (int ct = 0; ct < 4; ++ct) {
        float wi = W[((size_t)w * K + (K - 1)) * 64 + ct * 16 + c_lo];
        acc[ct] = f32x4{wi, wi, wi, wi};
    }
    const unsigned short* ab = ap + (size_t)G * NKC * 512 + l * 8;
    constexpr int D = (NKC < 8) ? NKC : 8;
#pragma unroll
    for (int h = 0; h < NKC / D; ++h) {
        // prefetch D A-fragments (independent, issued back-to-back)
        bf16x8 afs[D];
#pragma unroll
        for (int j = 0; j < D; ++j)
            afs[j] = *(const bf16x8*)(ab + (h * D + j) * 512);
        // B double-buffer, 1 chunk ahead
        bf16x8 bcur[4];
        {
            const unsigned short* wk = wp + (size_t)(h * D) * 8192 + w * 512 + l * 8;
#pragma unroll
            for (int i = 0; i < 4; ++i) bcur[i] = *(const bf16x8*)(wk + i * 2048);
        }
#pragma unroll
        for (int j = 0; j < D; ++j) {
            bf16x8 bnxt[4];
            if (j + 1 < D) {
                const unsigned short* wk = wp + (size_t)(h * D + j + 1) * 8192 + w * 512 + l * 8;
#pragma unroll
                for (int i = 0; i < 4; ++i) bnxt[i] = *(const bf16x8*)(wk + i * 2048);
            }
#pragma unroll
            for (int i = 0; i < 4; ++i)
                acc[i] = __builtin_amdgcn_mfma_f32_16x16x32_bf16(afs[j], bcur[i], acc[i], 0, 0, 0);
            if (j + 1 < D) {
#pragma unroll
                for (int i = 0; i < 4; ++i) bcur[i] = bnxt[i];
            }
        }
    }
}

// ---------------------------------------------------------------------------
// Fusion: block = 4 waves on ONE 16-node group (3125 blocks); wave w = rank w.
// Three separate passes (R9 structure — best measured); deep-prefetch inner.
// ---------------------------------------------------------------------------
__global__ __launch_bounds__(256) void fusion_mfma(
    const unsigned short* __restrict__ apc, const unsigned short* __restrict__ apt,
    const unsigned short* __restrict__ apr,
    const unsigned short* __restrict__ wpc, const unsigned short* __restrict__ wpt,
    const unsigned short* __restrict__ wpr,
    const float* __restrict__ Wc, const float* __restrict__ Wt, const float* __restrict__ Wr,
    const float* __restrict__ fw, const float* __restrict__ fb,
    unsigned short* __restrict__ h0b)
{
    __shared__ float lds[4096];   // 16KB rank-exchange
    const int w = threadIdx.x >> 6, l = threadIdx.x & 63;
    const int G = blockIdx.x;

    f32x4 prod[4], acc[4];
    fusion_pass_rank<129, 4>(apc, wpc, Wc, G, w, l, acc);
#pragma unroll
    for (int ct = 0; ct < 4; ++ct) prod[ct] = acc[ct];
    fusion_pass_rank<513, 16>(apt, wpt, Wt, G, w, l, acc);
#pragma unroll
    for (int ct = 0; ct < 4; ++ct) prod[ct] *= acc[ct];
    fusion_pass_rank<513, 16>(apr, wpr, Wr, G, w, l, acc);
    const float fww = fw[w];
#pragma unroll
    for (int ct = 0; ct < 4; ++ct) {
        prod[ct] = prod[ct] * acc[ct] * fww;
        *(f32x4*)&lds[((w * 4 + ct) * 64 + l) * 4] = prod[ct];
    }
    __syncthreads();

    // wave w sums the 4 ranks for col-tile ct = w
    f32x4 s = *(const f32x4*)&lds[((0 * 4 + w) * 64 + l) * 4];
#pragma unroll
    for (int r = 1; r < 4; ++r)
        s += *(const f32x4*)&lds[((r * 4 + w) * 64 + l) * 4];

    const int c = w * 16 + (l & 15);
    const float fbc = fb[c];
#pragma unroll
    for (int q = 0; q < 4; ++q) {
        int n = G * 16 + (l >> 4) * 4 + q;
        float v = s[q] + fbc;
        v = v > 0.f ? v : expm1f(v);
        h0b[(size_t)n * 64 + c] = f2b(v);
    }
}

// ---------------------------------------------------------------------------
// feat GEMM, register-streaming, ONE group per block, manual A prefetch +
// B rotation. Output HEAD-MINOR: featb[n][d*4+h].
// ---------------------------------------------------------------------------
template<int K>
__global__ __launch_bounds__(256) void gemm_reg(
    const unsigned short* __restrict__ Ab, const unsigned short* __restrict__ wp,
    unsigned short* __restrict__ featb)
{
    constexpr int NKC = K / 32;
    const int w = threadIdx.x >> 6, l = threadIdx.x & 63;
    const int nb = blockIdx.x * 16;

    f32x4 acc[4];
#pragma unroll
    for (int i = 0; i < 4; ++i) acc[i] = f32x4{0.f, 0.f, 0.f, 0.f};

    const unsigned short* abase = Ab + (size_t)(nb + (l & 15)) * K + (l >> 4) * 8;
    // prefetch all A-fragments (NKC <= 8 -> <= 32 VGPR)
    bf16x8 afs[NKC];
#pragma unroll
    for (int kc = 0; kc < NKC; ++kc)
        afs[kc] = *(const bf16x8*)(abase + kc * 32);

    bf16x8 bcur[4];
    {
        const unsigned short* wk = wp + (size_t)(0 * 16 + w * 4) * 512 + l * 8;
#pragma unroll
        for (int i = 0; i < 4; ++i) bcur[i] = *(const bf16x8*)(wk + i * 512);
    }
#pragma unroll
    for (int kc = 0; kc < NKC; ++kc) {
        bf16x8 bnxt[4];
        if (kc + 1 < NKC) {
            const unsigned short* wk = wp + ((size_t)(kc + 1) * 16 + w * 4) * 512 + l * 8;
#pragma unroll
            for (int i = 0; i < 4; ++i) bnxt[i] = *(const bf16x8*)(wk + i * 512);
        }
#pragma unroll
        for (int i = 0; i < 4; ++i)
            acc[i] = __builtin_amdgcn_mfma_f32_16x16x32_bf16(afs[kc], bcur[i], acc[i], 0, 0, 0);
        if (kc + 1 < NKC) {
#pragma unroll
            for (int i = 0; i < 4; ++i) bcur[i] = bnxt[i];
        }
    }
#pragma unroll
    for (int i = 0; i < 4; ++i) {
        int c = (w * 4 + i) * 16 + (l & 15);
        int dm = (c & 63) * 4 + (c >> 6);   // head-minor index
#pragma unroll
        for (int q = 0; q < 4; ++q) {
            int n = nb + (l >> 4) * 4 + q;
            featb[(size_t)n * 256 + dm] = f2b(acc[i][q]);
        }
    }
}

// ---------------------------------------------------------------------------
// el/er: one wave per node; head-minor feat -> single ushort4 load per lane.
// ---------------------------------------------------------------------------
__global__ __launch_bounds__(256) void elr_kernel(
    const unsigned short* __restrict__ featb,
    const float* __restrict__ al, const float* __restrict__ ar,
    float* __restrict__ el, float* __restrict__ er)
{
    int wid = (int)((blockIdx.x * (size_t)blockDim.x + threadIdx.x) >> 6);
    int lane = threadIdx.x & 63;
    if (wid >= NN) return;
    ushort4 f4 = *(const ushort4*)(featb + (size_t)wid * 256 + lane * 4);
    float x0 = b2f(f4.x), x1 = b2f(f4.y), x2 = b2f(f4.z), x3 = b2f(f4.w);
    float elh[4], erh[4];
    elh[0] = x0 * al[lane];        erh[0] = x0 * ar[lane];
    elh[1] = x1 * al[64 + lane];   erh[1] = x1 * ar[64 + lane];
    elh[2] = x2 * al[128 + lane];  erh[2] = x2 * ar[128 + lane];
    elh[3] = x3 * al[192 + lane];  erh[3] = x3 * ar[192 + lane];
#pragma unroll
    for (int off = 32; off; off >>= 1) {
#pragma unroll
        for (int h = 0; h < 4; ++h) {
            elh[h] += __shfl_xor(elh[h], off);
            erh[h] += __shfl_xor(erh[h], off);
        }
    }
    if (lane == 0) {
        *(float4*)(el + (size_t)wid * 4) = make_float4(elh[0], elh[1], elh[2], elh[3]);
        *(float4*)(er + (size_t)wid * 4) = make_float4(erh[0], erh[1], erh[2], erh[3]);
    }
}

// ---------------------------------------------------------------------------
// CSR build
// ---------------------------------------------------------------------------
__global__ void hist_kernel(const int* __restrict__ dst, int* __restrict__ cnt)
{
    int e = blockIdx.x * blockDim.x + threadIdx.x;
    if (e < EE) atomicAdd(&cnt[dst[e]], 1);
}

__global__ __launch_bounds__(1024) void scan_kernel(const int* __restrict__ cnt, int* __restrict__ offs)
{
    __shared__ int tmp[1024];
    const int t = threadIdx.x;
    const int C = (NN + 1023) / 1024;
    int lo = t * C, hi = min(lo + C, NN);
    int s = 0;
    for (int i = lo; i < hi; ++i) s += cnt[i];
    tmp[t] = s;
    __syncthreads();
    for (int off = 1; off < 1024; off <<= 1) {
        int v = (t >= off) ? tmp[t - off] : 0;
        __syncthreads();
        tmp[t] += v;
        __syncthreads();
    }
    int run = (t == 0) ? 0 : tmp[t - 1];
    for (int i = lo; i < hi; ++i) { offs[i] = run; run += cnt[i]; }
    if (t == 1023) offs[NN] = tmp[1023];
}

__global__ void scatter_kernel(const int* __restrict__ dst, const int* __restrict__ offs,
                               int* __restrict__ cur, int* __restrict__ esort)
{
    int e = blockIdx.x * blockDim.x + threadIdx.x;
    if (e < EE) {
        int d = dst[e];
        int p = offs[d] + atomicAdd(&cur[d], 1);
        esort[p] = e;
    }
}

// ---------------------------------------------------------------------------
// edge_prep: CSR-ordered logits + CSR-ordered src index.
// ---------------------------------------------------------------------------
__global__ void edge_prep(const int* __restrict__ esort, const int* __restrict__ src,
                          const int* __restrict__ dst,
                          const float* __restrict__ el, const float* __restrict__ er,
                          float4* __restrict__ eesort, int* __restrict__ srcsort)
{
    int p = blockIdx.x * blockDim.x + threadIdx.x;
    if (p >= EE) return;
    int e = esort[p];
    int s = src[e], d = dst[e];
    srcsort[p] = s;
    float4 l4 = *(const float4*)(el + (size_t)s * 4);
    float4 r4 = *(const float4*)(er + (size_t)d * 4);
    eesort[p] = make_float4(lrelu(l4.x + r4.x), lrelu(l4.y + r4.y),
                            lrelu(l4.z + r4.z), lrelu(l4.w + r4.w));
}

// ---------------------------------------------------------------------------
// Per-dst softmax + aggregation. One wave per node.
// Pass A: strided max. Pass B: strided exp writeback + z-sum.
// Pass C: serial edges x4-unrolled, weights ready-made, 1/z deferred.
// ---------------------------------------------------------------------------
template <int RESID, int WMZ, int WB16, int WF32>
__global__ __launch_bounds__(256) void gat_agg(
    const int* __restrict__ srcsort, const int* __restrict__ offs,
    const unsigned short* __restrict__ featb, float4* __restrict__ eesort,
    const unsigned short* __restrict__ residb, const float* __restrict__ bias,
    float* __restrict__ out, unsigned short* __restrict__ outb,
    float4* __restrict__ mbuf, float4* __restrict__ zbuf)
{
    int n = (int)((blockIdx.x * (size_t)blockDim.x + threadIdx.x) >> 6);
    int lane = threadIdx.x & 63;
    if (n >= NN) return;
    int s0 = offs[n], s1 = offs[n + 1];

    float m0 = -1e30f, m1 = -1e30f, m2 = -1e30f, m3 = -1e30f;
    for (int p = s0 + lane; p < s1; p += 64) {
        float4 v = eesort[p];
        m0 = fmaxf(m0, v.x); m1 = fmaxf(m1, v.y);
        m2 = fmaxf(m2, v.z); m3 = fmaxf(m3, v.w);
    }
#pragma unroll
    for (int off = 32; off; off >>= 1) {
        m0 = fmaxf(m0, __shfl_xor(m0, off));
        m1 = fmaxf(m1, __shfl_xor(m1, off));
        m2 = fmaxf(m2, __shfl_xor(m2, off));
        m3 = fmaxf(m3, __shfl_xor(m3, off));
    }

    float z0 = 0.f, z1 = 0.f, z2 = 0.f, z3 = 0.f;
    for (int p = s0 + lane; p < s1; p += 64) {
        float4 v = eesort[p];
        v.x = expf(v.x - m0); v.y = expf(v.y - m1);
        v.z = expf(v.z - m2); v.w = expf(v.w - m3);
        eesort[p] = v;
        z0 += v.x; z1 += v.y; z2 += v.z; z3 += v.w;
    }
    __threadfence_block();   // make lane-strided writebacks visible wave-wide
#pragma unroll
    for (int off = 32; off; off >>= 1) {
        z0 += __shfl_xor(z0, off);
        z1 += __shfl_xor(z1, off);
        z2 += __shfl_xor(z2, off);
        z3 += __shfl_xor(z3, off);
    }
    float i0 = z0 > 0.f ? 1.f / z0 : 0.f;
    float i1 = z1 > 0.f ? 1.f / z1 : 0.f;
    float i2 = z2 > 0.f ? 1.f / z2 : 0.f;
    float i3 = z3 > 0.f ? 1.f / z3 : 0.f;
    if (WMZ && lane == 0) {
        mbuf[n] = make_float4(m0, m1, m2, m3);
        zbuf[n] = make_float4(i0, i1, i2, i3);
    }

    float a0 = 0.f, a1 = 0.f, a2 = 0.f, a3 = 0.f;
    float c0 = 0.f, c1 = 0.f, c2 = 0.f, c3 = 0.f;
    int p = s0;
    for (; p + 3 < s1; p += 4) {
        float4 wA = eesort[p],     wB = eesort[p + 1];
        float4 wC = eesort[p + 2], wD = eesort[p + 3];
        int sA = srcsort[p],     sB = srcsort[p + 1];
        int sC = srcsort[p + 2], sD = srcsort[p + 3];
        ushort4 fA = *(const ushort4*)(featb + (size_t)sA * 256 + lane * 4);
        ushort4 fB = *(const ushort4*)(featb + (size_t)sB * 256 + lane * 4);
        ushort4 fC = *(const ushort4*)(featb + (size_t)sC * 256 + lane * 4);
        ushort4 fD = *(const ushort4*)(featb + (size_t)sD * 256 + lane * 4);
        a0 += wA.x * b2f(fA.x);  c0 += wB.x * b2f(fB.x);
        a1 += wA.y * b2f(fA.y);  c1 += wB.y * b2f(fB.y);
        a2 += wA.z * b2f(fA.z);  c2 += wB.z * b2f(fB.z);
        a3 += wA.w * b2f(fA.w);  c3 += wB.w * b2f(fB.w);
        a0 += wC.x * b2f(fC.x);  c0 += wD.x * b2f(fD.x);
        a1 += wC.y * b2f(fC.y);  c1 += wD.y * b2f(fD.y);
        a2 += wC.z * b2f(fC.z);  c2 += wD.z * b2f(fD.z);
        a3 += wC.w * b2f(fC.w);  c3 += wD.w * b2f(fD.w);
    }
    for (; p < s1; ++p) {
        float4 wA = eesort[p];
        int sA = srcsort[p];
        ushort4 fA = *(const ushort4*)(featb + (size_t)sA * 256 + lane * 4);
        a0 += wA.x * b2f(fA.x);
        a1 += wA.y * b2f(fA.y);
        a2 += wA.z * b2f(fA.z);
        a3 += wA.w * b2f(fA.w);
    }
    a0 += c0; a1 += c1; a2 += c2; a3 += c3;

    float o0 = a0 * i0 + bias[lane];
    float o1 = a1 * i1 + bias[64 + lane];
    float o2 = a2 * i2 + bias[128 + lane];
    float o3 = a3 * i3 + bias[192 + lane];
    if (RESID) {
        ushort4 rp = *(const ushort4*)(residb + (size_t)n * 256 + lane * 4);
        o0 += b2f(rp.x); o1 += b2f(rp.y); o2 += b2f(rp.z); o3 += b2f(rp.w);
    }
    if (WF32) {
        float* op = out + (size_t)n * 256;
        op[lane] = o0;
        op[64 + lane] = o1;
        op[128 + lane] = o2;
        op[192 + lane] = o3;
    }
    if (WB16) {
        ushort4 ob;
        ob.x = f2b(o0); ob.y = f2b(o1); ob.z = f2b(o2); ob.w = f2b(o3);
        *(ushort4*)(outb + (size_t)n * 256 + lane * 4) = ob;
    }
}

// ---------------------------------------------------------------------------
// att_final: att[e] = exp(lrelu(el[src]+er[dst]) - m[dst]) * i[dst]
// ---------------------------------------------------------------------------
__global__ void att_final(const int* __restrict__ src, const int* __restrict__ dst,
                          const float* __restrict__ el, const float* __restrict__ er,
                          const float4* __restrict__ mbuf, const float4* __restrict__ zbuf,
                          float4* __restrict__ att)
{
    int e = blockIdx.x * blockDim.x + threadIdx.x;
    if (e >= EE) return;
    int s = src[e], d = dst[e];
    float4 l4 = *(const float4*)(el + (size_t)s * 4);
    float4 r4 = *(const float4*)(er + (size_t)d * 4);
    float4 m4 = mbuf[d], zi = zbuf[d];
    att[e] = make_float4(expf(lrelu(l4.x + r4.x) - m4.x) * zi.x,
                         expf(lrelu(l4.y + r4.y) - m4.y) * zi.y,
                         expf(lrelu(l4.z + r4.z) - m4.z) * zi.z,
                         expf(lrelu(l4.w + r4.w) - m4.w) * zi.w);
}

// ---------------------------------------------------------------------------
extern "C" void kernel_launch(void* const* d_in, const int* in_sizes, int n_in,
                              void* d_out, int out_size, void* d_ws, size_t ws_size,
                              hipStream_t stream)
{
    const int*   src = (const int*)d_in[0];
    const int*   dst = (const int*)d_in[1];
    const float* hc  = (const float*)d_in[2];
    const float* ht  = (const float*)d_in[3];
    const float* hr  = (const float*)d_in[4];
    const float* Wc  = (const float*)d_in[5];
    const float* Wt  = (const float*)d_in[6];
    const float* Wr  = (const float*)d_in[7];
    const float* fw  = (const float*)d_in[8];
    const float* fb  = (const float*)d_in[9];
    const float* W0  = (const float*)d_in[10];
    const float* al0 = (const float*)d_in[11];
    const float* ar0 = (const float*)d_in[12];
    const float* b0  = (const float*)d_in[13];
    const float* W1  = (const float*)d_in[14];
    const float* al1 = (const float*)d_in[15];
    const float* ar1 = (const float*)d_in[16];
    const float* b1  = (const float*)d_in[17];

    // workspace layout (bytes); round-2 proved ws_size >= 69,200,064
    char* ws = (char*)d_ws;
    unsigned short* h0b   = (unsigned short*)(ws);               // N*64  bf16 :  6,400,000
    unsigned short* h1b   = (unsigned short*)(ws + 6400000);     // N*256 bf16 : 25,600,000 (head-minor)
    unsigned short* featb = (unsigned short*)(ws + 32000000);    // N*256 bf16 : 25,600,000 (head-minor)
    float* el    = (float*)(ws + 57600000);                      //    800,000
    float* er    = (float*)(ws + 58400000);                      //    800,000
    int*   cnt   = (int*)  (ws + 59200000);                      //    200,000
    int*   offs  = (int*)  (ws + 59400000);                      //    200,064 (padded)
    int*   esort = (int*)  (ws + 59600128);                      //  3,200,000
    unsigned short* wpc = (unsigned short*)(ws + 62800128);      //  4*16KB =  65,536
    unsigned short* wpt = (unsigned short*)(ws + 62865664);      // 16*16KB = 262,144
    unsigned short* wpr = (unsigned short*)(ws + 63127808);      // 16*16KB = 262,144
    unsigned short* wp0 = (unsigned short*)(ws + 63389952);      //  2*16KB =  32,768
    unsigned short* wp1 = (unsigned short*)(ws + 63422720);      //  8*16KB = 131,072
    float4* mbuf = (float4*)(ws + 63553792);                     //    800,000
    float4* zbuf = (float4*)(ws + 64353792);                     //    800,000
    int* srcsort = (int*)  (ws + 65153792);                      //  3,200,000
    if (ws_size < 68353792ull) return;                           // end of layout

    float* outh = (float*)d_out;                       // N*256 final h
    float4* atto = (float4*)(outh + (size_t)NN * 256); // E*4 att region

    // A-pack overlays (live only during fusion)
    unsigned short* apt = (unsigned short*)d_out;                     // 51,200,000
    unsigned short* apc = (unsigned short*)((char*)d_out + 51200000); // 12,800,000
    unsigned short* apr = (unsigned short*)(ws + 6400000);            // 51,200,000

    // weight packing
    pack_w_fusion<<<(4 * 16 * 64 + 255) / 256, 256, 0, stream>>>(Wc, wpc, 129, 4);
    pack_w_fusion<<<(16 * 16 * 64 + 255) / 256, 256, 0, stream>>>(Wt, wpt, 513, 16);
    pack_w_fusion<<<(16 * 16 * 64 + 255) / 256, 256, 0, stream>>>(Wr, wpr, 513, 16);
    pack_w_gemm<0><<<(2 * 16 * 64 + 255) / 256, 256, 0, stream>>>(W0, wp0, 64, 256);
    pack_w_gemm<1><<<(8 * 16 * 64 + 255) / 256, 256, 0, stream>>>(W1, wp1, 256, 256);

    // F1: feature packs (f32 -> bf16 A-fragment order), 128-k tiles
    pack_a_tile<129, 4><<<NG * 1, 256, 0, stream>>>(hc, apc);
    pack_a_tile<513, 16><<<NG * 4, 256, 0, stream>>>(ht, apt);
    pack_a_tile<513, 16><<<NG * 4, 256, 0, stream>>>(hr, apr);

    // F2: trilinear fusion (rank-split, manual deep prefetch)
    fusion_mfma<<<NG, 256, 0, stream>>>(apc, apt, apr, wpc, wpt, wpr,
                                        Wc, Wt, Wr, fw, fb, h0b);

    // CSR by dst
    hipMemsetAsync(cnt, 0, NN * sizeof(int), stream);
    hist_kernel<<<(EE + 255) / 256, 256, 0, stream>>>(dst, cnt);
    scan_kernel<<<1, 1024, 0, stream>>>(cnt, offs);
    hipMemsetAsync(cnt, 0, NN * sizeof(int), stream);
    scatter_kernel<<<(EE + 255) / 256, 256, 0, stream>>>(dst, offs, cnt, esort);

    // GAT layer 0: output only bf16 h1b (head-minor)
    gemm_reg<64><<<NG, 256, 0, stream>>>(h0b, wp0, featb);
    elr_kernel<<<(NN * 64 + 255) / 256, 256, 0, stream>>>(featb, al0, ar0, el, er);
    edge_prep<<<(EE + 255) / 256, 256, 0, stream>>>(esort, src, dst, el, er, atto, srcsort);
    gat_agg<0, 0, 1, 0><<<(NN * 64 + 255) / 256, 256, 0, stream>>>(
        srcsort, offs, featb, atto, nullptr, b0, nullptr, h1b, nullptr, nullptr);

    // GAT layer 1: residual from bf16 h1b; f32 out to d_out
    gemm_reg<256><<<NG, 256, 0, stream>>>(h1b, wp1, featb);
    elr_kernel<<<(NN * 64 + 255) / 256, 256, 0, stream>>>(featb, al1, ar1, el, er);
    edge_prep<<<(EE + 255) / 256, 256, 0, stream>>>(esort, src, dst, el, er, atto, srcsort);
    gat_agg<1, 1, 0, 1><<<(NN * 64 + 255) / 256, 256, 0, stream>>>(
        srcsort, offs, featb, atto, h1b, b1, outh, nullptr, mbuf, zbuf);
    att_final<<<(EE + 255) / 256, 256, 0, stream>>>(src, dst, el, er, mbuf, zbuf, atto);
}